// Round 15
// baseline (1381.238 us; speedup 1.0000x reference)
//
#include <hip/hip_runtime.h>
#include <cfloat>

#define N_PTS 4096
#define NB    4
#define KNN   20
#define EPSB  1e-5f
#define NSL   4          // knn candidate slices per batch-row (R12: NSL=8 regressed)

typedef short s8v __attribute__((ext_vector_type(8)));
typedef float f4v __attribute__((ext_vector_type(4)));

// ---------------------------------------------------------------------------
// bf16 hi/lo split (round-to-nearest-even both halves)
// ---------------------------------------------------------------------------
__device__ __forceinline__ void bf16split(float x, unsigned short* h, unsigned short* l)
{
    unsigned u = __builtin_bit_cast(unsigned, x);
    unsigned hb = (u + 0x7fffu + ((u >> 16) & 1u)) >> 16;
    float hf = __builtin_bit_cast(float, hb << 16);
    float res = x - hf;
    unsigned u2 = __builtin_bit_cast(unsigned, res);
    unsigned lb = (u2 + 0x7fffu + ((u2 >> 16) & 1u)) >> 16;
    *h = (unsigned short)hb;
    *l = (unsigned short)lb;
}

// ---------------------------------------------------------------------------
// Packed key: fp32 distance (top 24 bits: sign+exp+15 mantissa) | 8-bit
// lane-local candidate ordinal. d>=0 after clamp -> bit order == value order.
// 15 mantissa bits: R10's 11-bit variant FAILED (0.44); this passed (0.03).
// ---------------------------------------------------------------------------
__device__ __forceinline__ unsigned packkey(float d, int lc)
{
    d = fmaxf(d, 0.f);
    unsigned u = __builtin_bit_cast(unsigned, d);
    return (u & 0xFFFFFF00u) | (unsigned)lc;
}

// Branch-free sorted-insert: ascending bubble, 20x (v_min_u32 + v_max_u32).
__device__ __forceinline__ void insert20k(unsigned key, unsigned (&k20)[KNN])
{
#pragma unroll
    for (int j = 0; j < KNN; j++) {
        unsigned old = k20[j];
        unsigned lo = old < key ? old : key;
        key = old < key ? key : old;
        k20[j] = lo;
    }
}

// ---------------------------------------------------------------------------
// fp32 -> bf16 hi/lo split, transposed to [b][point][k] (MFMA fragment order).
// grid (N/64, B), block 256 (64 points x 4 k-octets). k >= C zero-filled.
// ---------------------------------------------------------------------------
__global__ __launch_bounds__(256)
void to_bf16_tr(const float* __restrict__ F, long bsF, int C, int KDP,
                unsigned short* __restrict__ Ghi, unsigned short* __restrict__ Glo)
{
    int b = blockIdx.y;
    int n = blockIdx.x * 64 + (threadIdx.x & 63);
    int kq = threadIdx.x >> 6;
    const float* Fb = F + (long)b * bsF;
    for (int k0 = kq * 8; k0 < KDP; k0 += 32) {
        s8v hv, lv;
#pragma unroll
        for (int i = 0; i < 8; i++) {
            int k = k0 + i;
            float x = (k < C) ? Fb[(long)k * N_PTS + n] : 0.f;
            unsigned short h, l;
            bf16split(x, &h, &l);
            hv[i] = (short)h;
            lv[i] = (short)l;
        }
        long o = ((long)b * N_PTS + n) * KDP + k0;
        *(s8v*)&Ghi[o] = hv;
        *(s8v*)&Glo[o] = lv;
    }
}

// ---------------------------------------------------------------------------
// MFMA fused distance + top-20, packed-key in-register selection,
// software-pipelined candidate stream with ASM-PINNED prefetch (R15).
// grid (N/64, NSL, B), block 256 (4 waves, one barrier pair total).
// Wave w: 16 queries x 1024 slice-candidates. Lane L: fixed query n=L&15,
// candidates quad*4+r per acc register (quad=L>>4) -> per-lane slice = 256
// candidates, lane-local ordinal lc = t*4+r (8 bits).
// R14 post-mortem: plain prefetch loads were SUNK back to use sites by the
// compiler (VGPR stayed 44, dur unchanged) - reloading is always legal, and
// its pressure heuristic prefers minimal registers, leaving ~1600 cyc of
// un-hidden L2 latency per t-step. Fix: empty inline-asm "+v" pins make the
// prefetched fragments opaque - the compiler cannot rematerialize/sink the
// loads, so they must complete into registers ahead of the current tile's
// MFMA+insert chain. Diagnostic: VGPR must jump to ~110-130.
// Out: knnd/knni [b][slice][N][KNN] sorted ascending (truncated dist).
// ---------------------------------------------------------------------------
template<int KDP>
__global__ __launch_bounds__(256, 3)
void fused_knn_mfma5(const unsigned short* __restrict__ Ghi,
                     const unsigned short* __restrict__ Glo,
                     const float* __restrict__ xx,
                     float* __restrict__ knnd, int* __restrict__ knni)
{
    constexpr int KS = KDP / 32;
    __shared__ unsigned mk[4][16][4][KNN];   // 20,480 B

    int tid = threadIdx.x;
    int w = tid >> 6, L = tid & 63;
    int n = L & 15;
    int quad = L >> 4;
    int b = blockIdx.z, slice = blockIdx.y;
    int q0 = blockIdx.x * 64, qw = w * 16;
    const unsigned short* Gh = Ghi + (long)b * N_PTS * KDP;
    const unsigned short* Gl = Glo + (long)b * N_PTS * KDP;
    const float* xxb = xx + (long)b * N_PTS;

    // persistent query fragments (hi+lo, all k-steps)
    s8v qhi[KS], qlo[KS];
    long qbase = (long)(q0 + qw + n) * KDP + quad * 8;
#pragma unroll
    for (int ks = 0; ks < KS; ks++) {
        qhi[ks] = *(const s8v*)&Gh[qbase + ks * 32];
        qlo[ks] = *(const s8v*)&Gl[qbase + ks * 32];
    }
    float xq = xxb[q0 + qw + n];

    unsigned k20[KNN];
#pragma unroll
    for (int j = 0; j < KNN; j++) k20[j] = 0xFFFFFFFFu;

    // pipeline prologue: load tile t=0 (pinned)
    long coff = (long)(slice * 1024 + n) * KDP + quad * 8;
    const float* xcp = xxb + slice * 1024 + quad * 4;
    s8v chi[KS], clo[KS];
#pragma unroll
    for (int ks = 0; ks < KS; ks++) {
        chi[ks] = *(const s8v*)&Gh[coff + ks * 32];
        clo[ks] = *(const s8v*)&Gl[coff + ks * 32];
    }
#pragma unroll
    for (int ks = 0; ks < KS; ks++)
        asm volatile("" : "+v"(chi[ks]), "+v"(clo[ks]));

    for (int t = 0; t < 64; t++) {
        // issue NEXT tile's loads first (consumed next iteration)
        long noff = coff + (t < 63 ? 16 * KDP : 0);
        s8v nhi[KS], nlo[KS];
#pragma unroll
        for (int ks = 0; ks < KS; ks++) {
            nhi[ks] = *(const s8v*)&Gh[noff + ks * 32];
            nlo[ks] = *(const s8v*)&Gl[noff + ks * 32];
        }
        // PIN: values become opaque -> loads cannot be sunk below this point
#pragma unroll
        for (int ks = 0; ks < KS; ks++)
            asm volatile("" : "+v"(nhi[ks]), "+v"(nlo[ks]));

        // compute on CURRENT tile (loads for t+1 in flight underneath)
        f4v acc = {0.f, 0.f, 0.f, 0.f};
#pragma unroll
        for (int ks = 0; ks < KS; ks++) {
            acc = __builtin_amdgcn_mfma_f32_16x16x32_bf16(chi[ks], qhi[ks], acc, 0, 0, 0);
            acc = __builtin_amdgcn_mfma_f32_16x16x32_bf16(chi[ks], qlo[ks], acc, 0, 0, 0);
            acc = __builtin_amdgcn_mfma_f32_16x16x32_bf16(clo[ks], qhi[ks], acc, 0, 0, 0);
        }
        float4 xc4 = *(const float4*)xcp;
        float xcv[4] = {xc4.x, xc4.y, xc4.z, xc4.w};
#pragma unroll
        for (int r = 0; r < 4; r++) {
            float d = xq + xcv[r] - 2.f * acc[r];
            insert20k(packkey(d, t * 4 + r), k20);
        }

        // rotate pipeline (register renames)
#pragma unroll
        for (int ks = 0; ks < KS; ks++) { chi[ks] = nhi[ks]; clo[ks] = nlo[ks]; }
        coff = noff;
        xcp += 16;
    }

    // publish per-lane lists, then 16 owner lanes merge 4 quad-slices/query
#pragma unroll
    for (int j = 0; j < KNN; j++) mk[w][n][quad][j] = k20[j];
    __syncthreads();
    if (L < 16) {
        int p[4] = {0, 0, 0, 0};
        long o = (((long)b * NSL + slice) * N_PTS + (q0 + qw + L)) * KNN;
#pragma unroll
        for (int j = 0; j < KNN; j++) {
            unsigned bd = 0xFFFFFF00u; int bi = 0x7fffffff; int bq = 0;
#pragma unroll
            for (int qd = 0; qd < 4; qd++) {
                unsigned kk = mk[w][L][qd][p[qd]];
                unsigned db = kk & 0xFFFFFF00u;
                int lc = (int)(kk & 0xFFu);
                int ci = slice * 1024 + (lc >> 2) * 16 + qd * 4 + (lc & 3);
                if (db < bd || (db == bd && ci < bi)) { bd = db; bi = ci; bq = qd; }
            }
            knnd[o + j] = __builtin_bit_cast(float, bd);
            knni[o + j] = bi;
            p[bq]++;
        }
    }
}

// ---------------------------------------------------------------------------
// Merge the NSL sorted slice lists per query -> final idx[b][i][KNN].
// Ties (equal truncated distance) broken by lower global index.
// ---------------------------------------------------------------------------
__global__ void knn_merge4(const float* __restrict__ knnd, const int* __restrict__ knni,
                           int* __restrict__ idxOut)
{
    int id = blockIdx.x * 256 + threadIdx.x;   // b*N + i
    int b = id / N_PTS, i = id % N_PTS;
    const float* dl[NSL]; const int* il[NSL];
#pragma unroll
    for (int qt = 0; qt < NSL; qt++) {
        dl[qt] = knnd + (((long)b * NSL + qt) * N_PTS + i) * KNN;
        il[qt] = knni + (((long)b * NSL + qt) * N_PTS + i) * KNN;
    }
    int p[NSL];
#pragma unroll
    for (int qt = 0; qt < NSL; qt++) p[qt] = 0;
    int* o = idxOut + (long)id * KNN;
#pragma unroll
    for (int j = 0; j < KNN; j++) {
        float best = FLT_MAX; int bi = 0x7fffffff; int bq = 0;
#pragma unroll
        for (int qt = 0; qt < NSL; qt++) {
            float vv = (p[qt] < KNN) ? dl[qt][p[qt]] : FLT_MAX;
            int   ci = (p[qt] < KNN) ? il[qt][p[qt]] : 0x7fffffff;
            if (vv < best || (vv == best && ci < bi)) { best = vv; bi = ci; bq = qt; }
        }
        o[j] = bi;
        p[bq]++;
    }
}

// ---------------------------------------------------------------------------
// Fused q/p MFMA GEMM (edge stages). A = point features (Ghi/Glo, [pt][k]),
// B = folded weights Wq/Wp bf16 hi/lo [cout][C]. Outputs point-major
// qv/pv [b][point][cout]; pv includes +shift.
// grid (N/64, cout/64, B), block 256 (4 waves x 16 points; 4 cout-chunks).
// ---------------------------------------------------------------------------
template<int KDP>
__global__ __launch_bounds__(256)
void qp_mfma(const unsigned short* __restrict__ Ghi,
             const unsigned short* __restrict__ Glo,
             const unsigned short* __restrict__ Wqh, const unsigned short* __restrict__ Wql,
             const unsigned short* __restrict__ Wph, const unsigned short* __restrict__ Wpl,
             const float* __restrict__ shf,
             float* __restrict__ qv, float* __restrict__ pv, int cout)
{
    constexpr int KS = KDP / 32;
    int tid = threadIdx.x;
    int w = tid >> 6, L = tid & 63;
    int n = L & 15, quad = L >> 4;
    int b = blockIdx.z;
    int p0 = blockIdx.x * 64 + w * 16;

    s8v ah[KS], al[KS];
    long abase = ((long)b * N_PTS + p0 + n) * KDP + quad * 8;
#pragma unroll
    for (int ks = 0; ks < KS; ks++) {
        ah[ks] = *(const s8v*)&Ghi[abase + ks * 32];
        al[ks] = *(const s8v*)&Glo[abase + ks * 32];
    }

#pragma unroll
    for (int oc4 = 0; oc4 < 4; oc4++) {
        int oc = blockIdx.y * 4 + oc4;
        long wbase = (long)(oc * 16 + n) * KDP + quad * 8;
        f4v aq = {0.f, 0.f, 0.f, 0.f};
        f4v ap = {0.f, 0.f, 0.f, 0.f};
#pragma unroll
        for (int ks = 0; ks < KS; ks++) {
            s8v wh = *(const s8v*)&Wqh[wbase + ks * 32];
            s8v wl = *(const s8v*)&Wql[wbase + ks * 32];
            aq = __builtin_amdgcn_mfma_f32_16x16x32_bf16(ah[ks], wh, aq, 0, 0, 0);
            aq = __builtin_amdgcn_mfma_f32_16x16x32_bf16(ah[ks], wl, aq, 0, 0, 0);
            aq = __builtin_amdgcn_mfma_f32_16x16x32_bf16(al[ks], wh, aq, 0, 0, 0);
            s8v ph = *(const s8v*)&Wph[wbase + ks * 32];
            s8v pl = *(const s8v*)&Wpl[wbase + ks * 32];
            ap = __builtin_amdgcn_mfma_f32_16x16x32_bf16(ah[ks], ph, ap, 0, 0, 0);
            ap = __builtin_amdgcn_mfma_f32_16x16x32_bf16(ah[ks], pl, ap, 0, 0, 0);
            ap = __builtin_amdgcn_mfma_f32_16x16x32_bf16(al[ks], ph, ap, 0, 0, 0);
        }
        float sv = shf[oc * 16 + n];
#pragma unroll
        for (int r = 0; r < 4; r++) {
            long pt = p0 + quad * 4 + r;
            long o = ((long)b * N_PTS + pt) * cout + oc * 16 + n;
            qv[o] = aq[r];
            pv[o] = ap[r] + sv;
        }
    }
}

// ---------------------------------------------------------------------------
// Stage-4 MFMA conv: Y[b][o][pt] = lrelu(sum_c W4[o][c]*cat[c][pt] + shift[o])
// A = W4 bf16 hi/lo [o][512]; B = catT bf16 hi/lo [b][pt][512].
// grid (N/16, B), block 256: 16 points shared, wave w owns o-chunks w*8..+7.
// ---------------------------------------------------------------------------
__global__ __launch_bounds__(256)
void conv4_mfma(const unsigned short* __restrict__ CTh, const unsigned short* __restrict__ CTl,
                const unsigned short* __restrict__ W4h, const unsigned short* __restrict__ W4l,
                const float* __restrict__ shf, float* __restrict__ Y)
{
    int tid = threadIdx.x;
    int w = tid >> 6, L = tid & 63;
    int n = L & 15, quad = L >> 4;
    int b = blockIdx.y;
    int p0 = blockIdx.x * 16;
    const unsigned short* cth = CTh + ((long)b * N_PTS + p0 + n) * 512 + quad * 8;
    const unsigned short* ctl = CTl + ((long)b * N_PTS + p0 + n) * 512 + quad * 8;

    f4v acc[8];
#pragma unroll
    for (int ch = 0; ch < 8; ch++) acc[ch] = {0.f, 0.f, 0.f, 0.f};

    for (int ks = 0; ks < 16; ks++) {
        s8v bh = *(const s8v*)&cth[ks * 32];
        s8v bl = *(const s8v*)&ctl[ks * 32];
#pragma unroll
        for (int ch = 0; ch < 8; ch++) {
            long o = (long)((w * 8 + ch) * 16 + n) * 512 + quad * 8 + ks * 32;
            s8v ahv = *(const s8v*)&W4h[o];
            s8v alv = *(const s8v*)&W4l[o];
            acc[ch] = __builtin_amdgcn_mfma_f32_16x16x32_bf16(ahv, bh, acc[ch], 0, 0, 0);
            acc[ch] = __builtin_amdgcn_mfma_f32_16x16x32_bf16(ahv, bl, acc[ch], 0, 0, 0);
            acc[ch] = __builtin_amdgcn_mfma_f32_16x16x32_bf16(alv, bh, acc[ch], 0, 0, 0);
        }
    }
#pragma unroll
    for (int ch = 0; ch < 8; ch++) {
#pragma unroll
        for (int r = 0; r < 4; r++) {
            int o = (w * 8 + ch) * 16 + quad * 4 + r;
            float y = acc[ch][r] + shf[o];
            y = y >= 0.f ? y : 0.2f * y;
            Y[((long)b * 512 + o) * N_PTS + p0 + n] = y;
        }
    }
}

// ---------------------------------------------------------------------------
// Weight folding to bf16 hi/lo, [o][c] layout (MFMA B-fragment order).
// ---------------------------------------------------------------------------
__global__ void fold_edge_bf16(const float* __restrict__ W, const float* __restrict__ g,
                               const float* __restrict__ bb, const float* __restrict__ m,
                               const float* __restrict__ v,
                               unsigned short* __restrict__ Wqh, unsigned short* __restrict__ Wql,
                               unsigned short* __restrict__ Wph, unsigned short* __restrict__ Wpl,
                               float* __restrict__ shift, int C, int cout)
{
    int id = blockIdx.x * 256 + threadIdx.x;
    if (id < C * cout) {
        int o = id / C;
        int c = id % C;
        float sc = g[o] * rsqrtf(v[o] + EPSB);
        float wd = W[(long)o * 2 * C + c];
        float wc = W[(long)o * 2 * C + C + c];
        bf16split(sc * wd, &Wqh[id], &Wql[id]);
        bf16split(sc * (wc - wd), &Wph[id], &Wpl[id]);
    }
    if (id < cout) {
        float sc = g[id] * rsqrtf(v[id] + EPSB);
        shift[id] = bb[id] - m[id] * sc;
    }
}

__global__ void fold_plain_bf16(const float* __restrict__ W, const float* __restrict__ g,
                                const float* __restrict__ bb, const float* __restrict__ m,
                                const float* __restrict__ v,
                                unsigned short* __restrict__ W4h, unsigned short* __restrict__ W4l,
                                float* __restrict__ shift, int C, int cout)
{
    int id = blockIdx.x * 256 + threadIdx.x;
    if (id < C * cout) {
        int o = id / C;
        int c = id % C;
        float sc = g[o] * rsqrtf(v[o] + EPSB);
        bf16split(sc * W[(long)o * C + c], &W4h[id], &W4l[id]);
    }
    if (id < cout) {
        float sc = g[id] * rsqrtf(v[id] + EPSB);
        shift[id] = bb[id] - m[id] * sc;
    }
}

// ---------------------------------------------------------------------------
__global__ void prep_xt_kernel(const float* __restrict__ x, float* __restrict__ xt)
{
    int id = blockIdx.x * 256 + threadIdx.x;    // < 4*3*4096
    int b = id / (3 * N_PTS);
    int rem = id % (3 * N_PTS);
    int c = rem / N_PTS;
    int i = rem % N_PTS;
    xt[id] = x[((long)b * N_PTS + i) * 3 + c];
}

__global__ void sqnorm_kernel(const float* __restrict__ F, float* __restrict__ xx,
                              int C, long bsF)
{
    int b = blockIdx.y;
    int j = blockIdx.x * 256 + threadIdx.x;
    const float* f = F + (long)b * bsF;
    float s = 0.f;
    for (int c = 0; c < C; c++) {
        float t = f[(long)c * N_PTS + j];
        s = fmaf(t, t, s);
    }
    xx[(long)b * N_PTS + j] = s;
}

__global__ void gather_max_kernel(const float* __restrict__ q, const float* __restrict__ p,
                                  const int* __restrict__ idx, float* __restrict__ cat,
                                  int cout, int c_off)
{
    int b = blockIdx.y;
    int i = blockIdx.x * 4 + threadIdx.y;
    int tx = threadIdx.x;
    const int* ip = idx + ((long)b * N_PTS + i) * KNN;
    int js[KNN];
#pragma unroll
    for (int k = 0; k < KNN; k++) js[k] = ip[k];
    const float* qb = q + (long)b * N_PTS * cout;
    const float* pb = p + ((long)b * N_PTS + i) * cout;
    float* ob = cat + ((long)b * 512 + c_off) * N_PTS + i;
    for (int o0 = 0; o0 < cout; o0 += 64) {
        int o = o0 + tx;
        float pv = pb[o];
        float mx = -FLT_MAX;
#pragma unroll
        for (int k = 0; k < KNN; k++) {
            float val = qb[(long)js[k] * cout + o] + pv;
            val = val >= 0.f ? val : 0.2f * val;
            mx = fmaxf(mx, val);
        }
        ob[(long)o * N_PTS] = mx;
    }
}

__global__ void edge0_kernel(const float* __restrict__ xt, const int* __restrict__ idx,
                             const float* __restrict__ W0, const float* __restrict__ g0,
                             const float* __restrict__ b0, const float* __restrict__ m0,
                             const float* __restrict__ v0, float* __restrict__ cat)
{
    int b = blockIdx.y;
    int i = blockIdx.x * 4 + threadIdx.y;
    int o = threadIdx.x;
    const float* xb = xt + (long)b * 3 * N_PTS;
    float cx = xb[i], cy = xb[N_PTS + i], cz = xb[2 * N_PTS + i];
    float w[9];
#pragma unroll
    for (int c = 0; c < 9; c++) w[c] = W0[o * 9 + c];
    float sc = g0[o] * rsqrtf(v0[o] + EPSB);
    float sh = b0[o] - m0[o] * sc;
    const int* ip = idx + ((long)b * N_PTS + i) * KNN;
    float mx = -FLT_MAX;
#pragma unroll
    for (int k = 0; k < KNN; k++) {
        int j = ip[k];
        float nx = xb[j], ny = xb[N_PTS + j], nz = xb[2 * N_PTS + j];
        float dx = nx - cx, dy = ny - cy, dz = nz - cz;
        float crx = cy * nz - cz * ny;
        float cry = cz * nx - cx * nz;
        float crz = cx * ny - cy * nx;
        float y = w[0] * dx + w[1] * dy + w[2] * dz
                + w[3] * crx + w[4] * cry + w[5] * crz
                + w[6] * cx + w[7] * cy + w[8] * cz;
        y = y * sc + sh;
        y = y >= 0.f ? y : 0.2f * y;
        mx = fmaxf(mx, y);
    }
    cat[((long)b * 512 + o) * N_PTS + i] = mx;
}

__global__ void rowmax_kernel(const float* __restrict__ Y, float* __restrict__ ymax)
{
    __shared__ float red[256];
    int b = blockIdx.y, o = blockIdx.x, t = threadIdx.x;
    const float* yb = Y + ((long)b * 512 + o) * N_PTS;
    float mx = -FLT_MAX;
#pragma unroll
    for (int s = 0; s < N_PTS / 256; s++) mx = fmaxf(mx, yb[t + 256 * s]);
    red[t] = mx;
    __syncthreads();
    for (int off = 128; off > 0; off >>= 1) {
        if (t < off) red[t] = fmaxf(red[t], red[t + off]);
        __syncthreads();
    }
    if (t == 0) ymax[(long)b * 512 + o] = red[0];
}

__global__ void head_kernel(const float* __restrict__ ymax, const float* __restrict__ We,
                            const float* __restrict__ Wh, const float* __restrict__ bh,
                            float* __restrict__ out)
{
    __shared__ float emb[128];
    __shared__ float yv[512];
    int b = blockIdx.x, t = threadIdx.x;
    for (int s = t; s < 512; s += 128) yv[s] = ymax[(long)b * 512 + s];
    __syncthreads();
    float acc = 0.f;
    for (int c = 0; c < 512; c++) acc = fmaf(yv[c], We[(long)t * 512 + c], acc);
    emb[t] = acc;
    __syncthreads();
    float acc2 = bh[t];
    for (int ff = 0; ff < 128; ff++) acc2 = fmaf(emb[ff], Wh[(long)t * 128 + ff], acc2);
    out[(long)b * 128 + t] = acc2;
}

// ---------------------------------------------------------------------------
extern "C" void kernel_launch(void* const* d_in, const int* in_sizes, int n_in,
                              void* d_out, int out_size, void* d_ws, size_t ws_size,
                              hipStream_t stream)
{
    const float* x = (const float*)d_in[0];
    const float *W[5], *g[5], *bb[5], *m[5], *v[5];
    for (int li = 0; li < 5; li++) {
        W[li]  = (const float*)d_in[1 + li * 5 + 0];
        g[li]  = (const float*)d_in[1 + li * 5 + 1];
        bb[li] = (const float*)d_in[1 + li * 5 + 2];
        m[li]  = (const float*)d_in[1 + li * 5 + 3];
        v[li]  = (const float*)d_in[1 + li * 5 + 4];
    }
    const float* We = (const float*)d_in[26];
    const float* Wh = (const float*)d_in[27];
    const float* bh = (const float*)d_in[28];
    float* out = (float*)d_out;

    // workspace carve (float units).
    float* ws   = (float*)d_ws;
    float* cat  = ws;                                   // 8,388,608 (B,512,N); stage4 Y reuses
    float* qbuf = cat + (long)8388608;                  // 8,388,608 multi-purpose
    float* pbuf = qbuf + (long)8388608;                 // 4,194,304 (p-values)
    int*   idxb = (int*)(pbuf + 4194304);               // 327,680 ints
    float* xt   = (float*)(idxb + 327680);              // 49,152
    float* xx   = xt + 49152;                           // 16,384
    unsigned short* Wqh = (unsigned short*)(xx + 16384);// 32,768 shorts each
    unsigned short* Wql = Wqh + 32768;
    unsigned short* Wph = Wql + 32768;
    unsigned short* Wpl = Wph + 32768;
    unsigned short* W4h = Wpl + 32768;                  // 262,144 shorts
    unsigned short* W4l = W4h + 262144;
    float* shf  = (float*)(W4l + 262144);               // 512
    float* ymax = shf + 512;                            // 2,048
    // qbuf internal layout:
    //  [0 .. 2,097,152) floats: Ghi/Glo (per-stage bf16 hi/lo, KDP<=128)
    //  [2,097,152 ..): knn slice lists (dead before qv written)
    //  [2,097,152 .. 6,291,456): qv (q-values, point-major)  [after knn]
    //  stage4: whole qbuf = catT hi (16MB) + catT lo (16MB)
    unsigned short* Ghi = (unsigned short*)qbuf;        // 2,097,152 shorts max
    unsigned short* Glo = Ghi + 2097152;
    float* knnd = qbuf + 2097152;                       // 1,310,720 floats
    int*   knni = (int*)(qbuf + 2097152 + 1310720);     // 1,310,720 ints
    float* qv   = qbuf + 2097152;                       // 4,194,304 floats (after knn)
    unsigned short* CTh = (unsigned short*)qbuf;        // 8,388,608 shorts
    unsigned short* CTl = CTh + 8388608;

    // ---- prep ----
    prep_xt_kernel<<<dim3(192), dim3(256), 0, stream>>>(x, xt);

    // ---- stage 0: knn on coords (C=3, K padded to 32) ----
    sqnorm_kernel<<<dim3(16, NB), dim3(256), 0, stream>>>(xt, xx, 3, (long)3 * N_PTS);
    to_bf16_tr<<<dim3(64, NB), dim3(256), 0, stream>>>(
        xt, (long)3 * N_PTS, 3, 32, Ghi, Glo);
    fused_knn_mfma5<32><<<dim3(64, NSL, NB), dim3(256), 0, stream>>>(
        Ghi, Glo, xx, knnd, knni);
    knn_merge4<<<dim3(64), dim3(256), 0, stream>>>(knnd, knni, idxb);
    edge0_kernel<<<dim3(N_PTS / 4, NB), dim3(64, 4), 0, stream>>>(
        xt, idxb, W[0], g[0], bb[0], m[0], v[0], cat);

    // ---- stages 1..3 ----
    const int Cs_[3]   = {64, 64, 128};
    const int co_[3]   = {64, 128, 256};
    const int inO_[3]  = {0, 64, 128};
    const int outO_[3] = {64, 128, 256};
    for (int s = 0; s < 3; s++) {
        int C = Cs_[s], cout = co_[s];
        const float* F = cat + (long)inO_[s] * N_PTS;   // batch stride 512*N
        sqnorm_kernel<<<dim3(16, NB), dim3(256), 0, stream>>>(F, xx, C, (long)512 * N_PTS);
        to_bf16_tr<<<dim3(64, NB), dim3(256), 0, stream>>>(
            F, (long)512 * N_PTS, C, C, Ghi, Glo);
        if (C == 64)
            fused_knn_mfma5<64><<<dim3(64, NSL, NB), dim3(256), 0, stream>>>(
                Ghi, Glo, xx, knnd, knni);
        else
            fused_knn_mfma5<128><<<dim3(64, NSL, NB), dim3(256), 0, stream>>>(
                Ghi, Glo, xx, knnd, knni);
        knn_merge4<<<dim3(64), dim3(256), 0, stream>>>(knnd, knni, idxb);

        int li = s + 1;
        fold_edge_bf16<<<dim3((C * cout + 255) / 256), dim3(256), 0, stream>>>(
            W[li], g[li], bb[li], m[li], v[li], Wqh, Wql, Wph, Wpl, shf, C, cout);
        if (C == 64)
            qp_mfma<64><<<dim3(64, cout / 64, NB), dim3(256), 0, stream>>>(
                Ghi, Glo, Wqh, Wql, Wph, Wpl, shf, qv, pbuf, cout);
        else
            qp_mfma<128><<<dim3(64, cout / 64, NB), dim3(256), 0, stream>>>(
                Ghi, Glo, Wqh, Wql, Wph, Wpl, shf, qv, pbuf, cout);
        gather_max_kernel<<<dim3(N_PTS / 4, NB), dim3(64, 4), 0, stream>>>(
            qv, pbuf, idxb, cat, cout, outO_[s]);
    }

    // ---- stage 4: MFMA pointwise conv + bn + lrelu ----
    fold_plain_bf16<<<dim3((512 * 512 + 255) / 256), dim3(256), 0, stream>>>(
        W[4], g[4], bb[4], m[4], v[4], W4h, W4l, shf, 512, 512);
    to_bf16_tr<<<dim3(64, NB), dim3(256), 0, stream>>>(
        cat, (long)512 * N_PTS, 512, 512, CTh, CTl);
    conv4_mfma<<<dim3(N_PTS / 16, NB), dim3(256), 0, stream>>>(
        CTh, CTl, W4h, W4l, shf, cat);   // Y overwrites dead fp32 cat

    // ---- global max + head ----
    rowmax_kernel<<<dim3(512, NB), dim3(256), 0, stream>>>(cat, ymax);
    head_kernel<<<dim3(NB), dim3(128), 0, stream>>>(ymax, We, Wh, bh, out);
}

// Round 16
// 1220.119 us; speedup vs baseline: 1.1321x; 1.1321x over previous
//
#include <hip/hip_runtime.h>
#include <cfloat>

#define N_PTS 4096
#define NB    4
#define KNN   20
#define EPSB  1e-5f
#define NSL   4          // knn candidate slices per batch-row

typedef short s8v __attribute__((ext_vector_type(8)));
typedef float f4v __attribute__((ext_vector_type(4)));

// ---------------------------------------------------------------------------
// bf16 hi/lo split (round-to-nearest-even both halves)
// ---------------------------------------------------------------------------
__device__ __forceinline__ void bf16split(float x, unsigned short* h, unsigned short* l)
{
    unsigned u = __builtin_bit_cast(unsigned, x);
    unsigned hb = (u + 0x7fffu + ((u >> 16) & 1u)) >> 16;
    float hf = __builtin_bit_cast(float, hb << 16);
    float res = x - hf;
    unsigned u2 = __builtin_bit_cast(unsigned, res);
    unsigned lb = (u2 + 0x7fffu + ((u2 >> 16) & 1u)) >> 16;
    *h = (unsigned short)hb;
    *l = (unsigned short)lb;
}

// ---------------------------------------------------------------------------
// Packed key: fp32 distance (top 24 bits) | 8-bit lane-local ordinal.
// 15 mantissa bits: R10's 11-bit variant FAILED (0.44); this passed (0.03).
// ---------------------------------------------------------------------------
__device__ __forceinline__ unsigned packkey(float d, int lc)
{
    d = fmaxf(d, 0.f);
    unsigned u = __builtin_bit_cast(unsigned, d);
    return (u & 0xFFFFFF00u) | (unsigned)lc;
}

// Branch-free sorted-insert: ascending bubble, 20x (v_min_u32 + v_max_u32).
__device__ __forceinline__ void insert20k(unsigned key, unsigned (&k20)[KNN])
{
#pragma unroll
    for (int j = 0; j < KNN; j++) {
        unsigned old = k20[j];
        unsigned lo = old < key ? old : key;
        key = old < key ? key : old;
        k20[j] = lo;
    }
}

// async global->LDS, 16B per lane; LDS dest = wave-uniform base + lane*16
__device__ __forceinline__ void gl2lds16(const void* g, void* l)
{
    __builtin_amdgcn_global_load_lds(
        (const __attribute__((address_space(1))) unsigned int*)g,
        (__attribute__((address_space(3))) unsigned int*)l,
        16, 0, 0);
}

// ---------------------------------------------------------------------------
// fp32 -> bf16 hi/lo split, transposed to [b][point][k] (MFMA fragment order).
// grid (N/64, B), block 256 (64 points x 4 k-octets). k >= C zero-filled.
// ---------------------------------------------------------------------------
__global__ __launch_bounds__(256)
void to_bf16_tr(const float* __restrict__ F, long bsF, int C, int KDP,
                unsigned short* __restrict__ Ghi, unsigned short* __restrict__ Glo)
{
    int b = blockIdx.y;
    int n = blockIdx.x * 64 + (threadIdx.x & 63);
    int kq = threadIdx.x >> 6;
    const float* Fb = F + (long)b * bsF;
    for (int k0 = kq * 8; k0 < KDP; k0 += 32) {
        s8v hv, lv;
#pragma unroll
        for (int i = 0; i < 8; i++) {
            int k = k0 + i;
            float x = (k < C) ? Fb[(long)k * N_PTS + n] : 0.f;
            unsigned short h, l;
            bf16split(x, &h, &l);
            hv[i] = (short)h;
            lv[i] = (short)l;
        }
        long o = ((long)b * N_PTS + n) * KDP + k0;
        *(s8v*)&Ghi[o] = hv;
        *(s8v*)&Glo[o] = lv;
    }
}

// ---------------------------------------------------------------------------
// MFMA fused distance + top-20, packed-key in-register selection,
// LDS-staged candidate tiles (R16).
// grid (N/64, NSL, B), block 256 (4 waves).
// R15 post-mortem: all 4 waves in a block stream IDENTICAL candidate
// fragments (cbase independent of w) -> 4 GB of L2 reads per dispatch
// (~15 TB/s, at the L2 ceiling) - the stall was L2 bandwidth, which is why
// occupancy (R12) and register pipelining (R13-R15) were all neutral.
// Fix: each 16-candidate tile is 4KB CONTIGUOUS in G -> stage it once per
// block into double-buffered LDS via global_load_lds (width 16; one issue
// per 256 threads per array), prefetch t+1 while computing t, one barrier
// per tile (compiler drains vmcnt before s_barrier). L2 traffic /4, t-loop
// global loads 9 -> 1 per wave-step.
// Out: knnd/knni [b][slice][N][KNN] sorted ascending (truncated dist).
// ---------------------------------------------------------------------------
template<int KDP>
__global__ __launch_bounds__(256, 3)
void fused_knn_mfma6(const unsigned short* __restrict__ Ghi,
                     const unsigned short* __restrict__ Glo,
                     const float* __restrict__ xx,
                     float* __restrict__ knnd, int* __restrict__ knni)
{
    constexpr int KS = KDP / 32;
    constexpr int TS = 16 * KDP;          // shorts per tile per array
    constexpr int NCH = (TS * 2) / 16;    // 16B chunks per array per tile
    __shared__ short cbuf[2][2][TS];      // [buf][hi/lo][tile]
    __shared__ unsigned mk[4][16][4][KNN];

    int tid = threadIdx.x;
    int w = tid >> 6, L = tid & 63;
    int n = L & 15;
    int quad = L >> 4;
    int b = blockIdx.z, slice = blockIdx.y;
    int q0 = blockIdx.x * 64, qw = w * 16;
    const unsigned short* Gh = Ghi + (long)b * N_PTS * KDP;
    const unsigned short* Gl = Glo + (long)b * N_PTS * KDP;
    const float* xxb = xx + (long)b * N_PTS;

    // persistent query fragments (global, once)
    s8v qhi[KS], qlo[KS];
    long qbase = (long)(q0 + qw + n) * KDP + quad * 8;
#pragma unroll
    for (int ks = 0; ks < KS; ks++) {
        qhi[ks] = *(const s8v*)&Gh[qbase + ks * 32];
        qlo[ks] = *(const s8v*)&Gl[qbase + ks * 32];
    }
    float xq = xxb[q0 + qw + n];

    unsigned k20[KNN];
#pragma unroll
    for (int j = 0; j < KNN; j++) k20[j] = 0xFFFFFFFFu;

    // prologue: stage tile 0 into buf 0
    int w64 = tid & 192;                  // wave base (uniform per wave)
    {
        long tb = (long)(slice * 1024) * KDP;
        if (tid < NCH) {
            gl2lds16((const char*)(Gh + tb) + tid * 16,
                     (char*)&cbuf[0][0][0] + w64 * 16);
            gl2lds16((const char*)(Gl + tb) + tid * 16,
                     (char*)&cbuf[0][1][0] + w64 * 16);
        }
    }
    __syncthreads();

    const float* xcp = xxb + slice * 1024 + quad * 4;
    int fo = n * KDP + quad * 8;          // fragment offset within tile

    for (int t = 0; t < 64; t++) {
        int cur = t & 1;
        // prefetch tile t+1 into the other buffer (async, no reg round-trip)
        if (t < 63 && tid < NCH) {
            long tb = (long)(slice * 1024 + (t + 1) * 16) * KDP;
            gl2lds16((const char*)(Gh + tb) + tid * 16,
                     (char*)&cbuf[cur ^ 1][0][0] + w64 * 16);
            gl2lds16((const char*)(Gl + tb) + tid * 16,
                     (char*)&cbuf[cur ^ 1][1][0] + w64 * 16);
        }

        // compute on current tile from LDS
        const short* Ch = &cbuf[cur][0][0];
        const short* Cl = &cbuf[cur][1][0];
        f4v acc = {0.f, 0.f, 0.f, 0.f};
#pragma unroll
        for (int ks = 0; ks < KS; ks++) {
            s8v chi = *(const s8v*)&Ch[fo + ks * 32];
            s8v clo = *(const s8v*)&Cl[fo + ks * 32];
            acc = __builtin_amdgcn_mfma_f32_16x16x32_bf16(chi, qhi[ks], acc, 0, 0, 0);
            acc = __builtin_amdgcn_mfma_f32_16x16x32_bf16(chi, qlo[ks], acc, 0, 0, 0);
            acc = __builtin_amdgcn_mfma_f32_16x16x32_bf16(clo, qhi[ks], acc, 0, 0, 0);
        }
        float4 xc4 = *(const float4*)xcp;
        float xcv[4] = {xc4.x, xc4.y, xc4.z, xc4.w};
#pragma unroll
        for (int r = 0; r < 4; r++) {
            float d = xq + xcv[r] - 2.f * acc[r];
            insert20k(packkey(d, t * 4 + r), k20);
        }
        xcp += 16;
        __syncthreads();   // drains prefetch (vmcnt) + frees cur buffer
    }

    // publish per-lane lists, then 16 owner lanes merge 4 quad-slices/query
#pragma unroll
    for (int j = 0; j < KNN; j++) mk[w][n][quad][j] = k20[j];
    __syncthreads();
    if (L < 16) {
        int p[4] = {0, 0, 0, 0};
        long o = (((long)b * NSL + slice) * N_PTS + (q0 + qw + L)) * KNN;
#pragma unroll
        for (int j = 0; j < KNN; j++) {
            unsigned bd = 0xFFFFFF00u; int bi = 0x7fffffff; int bq = 0;
#pragma unroll
            for (int qd = 0; qd < 4; qd++) {
                unsigned kk = mk[w][L][qd][p[qd]];
                unsigned db = kk & 0xFFFFFF00u;
                int lc = (int)(kk & 0xFFu);
                int ci = slice * 1024 + (lc >> 2) * 16 + qd * 4 + (lc & 3);
                if (db < bd || (db == bd && ci < bi)) { bd = db; bi = ci; bq = qd; }
            }
            knnd[o + j] = __builtin_bit_cast(float, bd);
            knni[o + j] = bi;
            p[bq]++;
        }
    }
}

// ---------------------------------------------------------------------------
// Merge the NSL sorted slice lists per query -> final idx[b][i][KNN].
// Ties (equal truncated distance) broken by lower global index.
// ---------------------------------------------------------------------------
__global__ void knn_merge4(const float* __restrict__ knnd, const int* __restrict__ knni,
                           int* __restrict__ idxOut)
{
    int id = blockIdx.x * 256 + threadIdx.x;   // b*N + i
    int b = id / N_PTS, i = id % N_PTS;
    const float* dl[NSL]; const int* il[NSL];
#pragma unroll
    for (int qt = 0; qt < NSL; qt++) {
        dl[qt] = knnd + (((long)b * NSL + qt) * N_PTS + i) * KNN;
        il[qt] = knni + (((long)b * NSL + qt) * N_PTS + i) * KNN;
    }
    int p[NSL];
#pragma unroll
    for (int qt = 0; qt < NSL; qt++) p[qt] = 0;
    int* o = idxOut + (long)id * KNN;
#pragma unroll
    for (int j = 0; j < KNN; j++) {
        float best = FLT_MAX; int bi = 0x7fffffff; int bq = 0;
#pragma unroll
        for (int qt = 0; qt < NSL; qt++) {
            float vv = (p[qt] < KNN) ? dl[qt][p[qt]] : FLT_MAX;
            int   ci = (p[qt] < KNN) ? il[qt][p[qt]] : 0x7fffffff;
            if (vv < best || (vv == best && ci < bi)) { best = vv; bi = ci; bq = qt; }
        }
        o[j] = bi;
        p[bq]++;
    }
}

// ---------------------------------------------------------------------------
// Fused q/p MFMA GEMM (edge stages). A = point features (Ghi/Glo, [pt][k]),
// B = folded weights Wq/Wp bf16 hi/lo [cout][C]. Outputs point-major
// qv/pv [b][point][cout]; pv includes +shift.
// grid (N/64, cout/64, B), block 256 (4 waves x 16 points; 4 cout-chunks).
// ---------------------------------------------------------------------------
template<int KDP>
__global__ __launch_bounds__(256)
void qp_mfma(const unsigned short* __restrict__ Ghi,
             const unsigned short* __restrict__ Glo,
             const unsigned short* __restrict__ Wqh, const unsigned short* __restrict__ Wql,
             const unsigned short* __restrict__ Wph, const unsigned short* __restrict__ Wpl,
             const float* __restrict__ shf,
             float* __restrict__ qv, float* __restrict__ pv, int cout)
{
    constexpr int KS = KDP / 32;
    int tid = threadIdx.x;
    int w = tid >> 6, L = tid & 63;
    int n = L & 15, quad = L >> 4;
    int b = blockIdx.z;
    int p0 = blockIdx.x * 64 + w * 16;

    s8v ah[KS], al[KS];
    long abase = ((long)b * N_PTS + p0 + n) * KDP + quad * 8;
#pragma unroll
    for (int ks = 0; ks < KS; ks++) {
        ah[ks] = *(const s8v*)&Ghi[abase + ks * 32];
        al[ks] = *(const s8v*)&Glo[abase + ks * 32];
    }

#pragma unroll
    for (int oc4 = 0; oc4 < 4; oc4++) {
        int oc = blockIdx.y * 4 + oc4;
        long wbase = (long)(oc * 16 + n) * KDP + quad * 8;
        f4v aq = {0.f, 0.f, 0.f, 0.f};
        f4v ap = {0.f, 0.f, 0.f, 0.f};
#pragma unroll
        for (int ks = 0; ks < KS; ks++) {
            s8v wh = *(const s8v*)&Wqh[wbase + ks * 32];
            s8v wl = *(const s8v*)&Wql[wbase + ks * 32];
            aq = __builtin_amdgcn_mfma_f32_16x16x32_bf16(ah[ks], wh, aq, 0, 0, 0);
            aq = __builtin_amdgcn_mfma_f32_16x16x32_bf16(ah[ks], wl, aq, 0, 0, 0);
            aq = __builtin_amdgcn_mfma_f32_16x16x32_bf16(al[ks], wh, aq, 0, 0, 0);
            s8v ph = *(const s8v*)&Wph[wbase + ks * 32];
            s8v pl = *(const s8v*)&Wpl[wbase + ks * 32];
            ap = __builtin_amdgcn_mfma_f32_16x16x32_bf16(ah[ks], ph, ap, 0, 0, 0);
            ap = __builtin_amdgcn_mfma_f32_16x16x32_bf16(ah[ks], pl, ap, 0, 0, 0);
            ap = __builtin_amdgcn_mfma_f32_16x16x32_bf16(al[ks], ph, ap, 0, 0, 0);
        }
        float sv = shf[oc * 16 + n];
#pragma unroll
        for (int r = 0; r < 4; r++) {
            long pt = p0 + quad * 4 + r;
            long o = ((long)b * N_PTS + pt) * cout + oc * 16 + n;
            qv[o] = aq[r];
            pv[o] = ap[r] + sv;
        }
    }
}

// ---------------------------------------------------------------------------
// Stage-4 MFMA conv: Y[b][o][pt] = lrelu(sum_c W4[o][c]*cat[c][pt] + shift[o])
// A = W4 bf16 hi/lo [o][512]; B = catT bf16 hi/lo [b][pt][512].
// grid (N/16, B), block 256: 16 points shared, wave w owns o-chunks w*8..+7.
// ---------------------------------------------------------------------------
__global__ __launch_bounds__(256)
void conv4_mfma(const unsigned short* __restrict__ CTh, const unsigned short* __restrict__ CTl,
                const unsigned short* __restrict__ W4h, const unsigned short* __restrict__ W4l,
                const float* __restrict__ shf, float* __restrict__ Y)
{
    int tid = threadIdx.x;
    int w = tid >> 6, L = tid & 63;
    int n = L & 15, quad = L >> 4;
    int b = blockIdx.y;
    int p0 = blockIdx.x * 16;
    const unsigned short* cth = CTh + ((long)b * N_PTS + p0 + n) * 512 + quad * 8;
    const unsigned short* ctl = CTl + ((long)b * N_PTS + p0 + n) * 512 + quad * 8;

    f4v acc[8];
#pragma unroll
    for (int ch = 0; ch < 8; ch++) acc[ch] = {0.f, 0.f, 0.f, 0.f};

    for (int ks = 0; ks < 16; ks++) {
        s8v bh = *(const s8v*)&cth[ks * 32];
        s8v bl = *(const s8v*)&ctl[ks * 32];
#pragma unroll
        for (int ch = 0; ch < 8; ch++) {
            long o = (long)((w * 8 + ch) * 16 + n) * 512 + quad * 8 + ks * 32;
            s8v ahv = *(const s8v*)&W4h[o];
            s8v alv = *(const s8v*)&W4l[o];
            acc[ch] = __builtin_amdgcn_mfma_f32_16x16x32_bf16(ahv, bh, acc[ch], 0, 0, 0);
            acc[ch] = __builtin_amdgcn_mfma_f32_16x16x32_bf16(ahv, bl, acc[ch], 0, 0, 0);
            acc[ch] = __builtin_amdgcn_mfma_f32_16x16x32_bf16(alv, bh, acc[ch], 0, 0, 0);
        }
    }
#pragma unroll
    for (int ch = 0; ch < 8; ch++) {
#pragma unroll
        for (int r = 0; r < 4; r++) {
            int o = (w * 8 + ch) * 16 + quad * 4 + r;
            float y = acc[ch][r] + shf[o];
            y = y >= 0.f ? y : 0.2f * y;
            Y[((long)b * 512 + o) * N_PTS + p0 + n] = y;
        }
    }
}

// ---------------------------------------------------------------------------
// Weight folding to bf16 hi/lo, [o][c] layout (MFMA B-fragment order).
// ---------------------------------------------------------------------------
__global__ void fold_edge_bf16(const float* __restrict__ W, const float* __restrict__ g,
                               const float* __restrict__ bb, const float* __restrict__ m,
                               const float* __restrict__ v,
                               unsigned short* __restrict__ Wqh, unsigned short* __restrict__ Wql,
                               unsigned short* __restrict__ Wph, unsigned short* __restrict__ Wpl,
                               float* __restrict__ shift, int C, int cout)
{
    int id = blockIdx.x * 256 + threadIdx.x;
    if (id < C * cout) {
        int o = id / C;
        int c = id % C;
        float sc = g[o] * rsqrtf(v[o] + EPSB);
        float wd = W[(long)o * 2 * C + c];
        float wc = W[(long)o * 2 * C + C + c];
        bf16split(sc * wd, &Wqh[id], &Wql[id]);
        bf16split(sc * (wc - wd), &Wph[id], &Wpl[id]);
    }
    if (id < cout) {
        float sc = g[id] * rsqrtf(v[id] + EPSB);
        shift[id] = bb[id] - m[id] * sc;
    }
}

__global__ void fold_plain_bf16(const float* __restrict__ W, const float* __restrict__ g,
                                const float* __restrict__ bb, const float* __restrict__ m,
                                const float* __restrict__ v,
                                unsigned short* __restrict__ W4h, unsigned short* __restrict__ W4l,
                                float* __restrict__ shift, int C, int cout)
{
    int id = blockIdx.x * 256 + threadIdx.x;
    if (id < C * cout) {
        int o = id / C;
        int c = id % C;
        float sc = g[o] * rsqrtf(v[o] + EPSB);
        bf16split(sc * W[(long)o * C + c], &W4h[id], &W4l[id]);
    }
    if (id < cout) {
        float sc = g[id] * rsqrtf(v[id] + EPSB);
        shift[id] = bb[id] - m[id] * sc;
    }
}

// ---------------------------------------------------------------------------
__global__ void prep_xt_kernel(const float* __restrict__ x, float* __restrict__ xt)
{
    int id = blockIdx.x * 256 + threadIdx.x;    // < 4*3*4096
    int b = id / (3 * N_PTS);
    int rem = id % (3 * N_PTS);
    int c = rem / N_PTS;
    int i = rem % N_PTS;
    xt[id] = x[((long)b * N_PTS + i) * 3 + c];
}

__global__ void sqnorm_kernel(const float* __restrict__ F, float* __restrict__ xx,
                              int C, long bsF)
{
    int b = blockIdx.y;
    int j = blockIdx.x * 256 + threadIdx.x;
    const float* f = F + (long)b * bsF;
    float s = 0.f;
    for (int c = 0; c < C; c++) {
        float t = f[(long)c * N_PTS + j];
        s = fmaf(t, t, s);
    }
    xx[(long)b * N_PTS + j] = s;
}

__global__ void gather_max_kernel(const float* __restrict__ q, const float* __restrict__ p,
                                  const int* __restrict__ idx, float* __restrict__ cat,
                                  int cout, int c_off)
{
    int b = blockIdx.y;
    int i = blockIdx.x * 4 + threadIdx.y;
    int tx = threadIdx.x;
    const int* ip = idx + ((long)b * N_PTS + i) * KNN;
    int js[KNN];
#pragma unroll
    for (int k = 0; k < KNN; k++) js[k] = ip[k];
    const float* qb = q + (long)b * N_PTS * cout;
    const float* pb = p + ((long)b * N_PTS + i) * cout;
    float* ob = cat + ((long)b * 512 + c_off) * N_PTS + i;
    for (int o0 = 0; o0 < cout; o0 += 64) {
        int o = o0 + tx;
        float pv = pb[o];
        float mx = -FLT_MAX;
#pragma unroll
        for (int k = 0; k < KNN; k++) {
            float val = qb[(long)js[k] * cout + o] + pv;
            val = val >= 0.f ? val : 0.2f * val;
            mx = fmaxf(mx, val);
        }
        ob[(long)o * N_PTS] = mx;
    }
}

__global__ void edge0_kernel(const float* __restrict__ xt, const int* __restrict__ idx,
                             const float* __restrict__ W0, const float* __restrict__ g0,
                             const float* __restrict__ b0, const float* __restrict__ m0,
                             const float* __restrict__ v0, float* __restrict__ cat)
{
    int b = blockIdx.y;
    int i = blockIdx.x * 4 + threadIdx.y;
    int o = threadIdx.x;
    const float* xb = xt + (long)b * 3 * N_PTS;
    float cx = xb[i], cy = xb[N_PTS + i], cz = xb[2 * N_PTS + i];
    float w[9];
#pragma unroll
    for (int c = 0; c < 9; c++) w[c] = W0[o * 9 + c];
    float sc = g0[o] * rsqrtf(v0[o] + EPSB);
    float sh = b0[o] - m0[o] * sc;
    const int* ip = idx + ((long)b * N_PTS + i) * KNN;
    float mx = -FLT_MAX;
#pragma unroll
    for (int k = 0; k < KNN; k++) {
        int j = ip[k];
        float nx = xb[j], ny = xb[N_PTS + j], nz = xb[2 * N_PTS + j];
        float dx = nx - cx, dy = ny - cy, dz = nz - cz;
        float crx = cy * nz - cz * ny;
        float cry = cz * nx - cx * nz;
        float crz = cx * ny - cy * nx;
        float y = w[0] * dx + w[1] * dy + w[2] * dz
                + w[3] * crx + w[4] * cry + w[5] * crz
                + w[6] * cx + w[7] * cy + w[8] * cz;
        y = y * sc + sh;
        y = y >= 0.f ? y : 0.2f * y;
        mx = fmaxf(mx, y);
    }
    cat[((long)b * 512 + o) * N_PTS + i] = mx;
}

__global__ void rowmax_kernel(const float* __restrict__ Y, float* __restrict__ ymax)
{
    __shared__ float red[256];
    int b = blockIdx.y, o = blockIdx.x, t = threadIdx.x;
    const float* yb = Y + ((long)b * 512 + o) * N_PTS;
    float mx = -FLT_MAX;
#pragma unroll
    for (int s = 0; s < N_PTS / 256; s++) mx = fmaxf(mx, yb[t + 256 * s]);
    red[t] = mx;
    __syncthreads();
    for (int off = 128; off > 0; off >>= 1) {
        if (t < off) red[t] = fmaxf(red[t], red[t + off]);
        __syncthreads();
    }
    if (t == 0) ymax[(long)b * 512 + o] = red[0];
}

__global__ void head_kernel(const float* __restrict__ ymax, const float* __restrict__ We,
                            const float* __restrict__ Wh, const float* __restrict__ bh,
                            float* __restrict__ out)
{
    __shared__ float emb[128];
    __shared__ float yv[512];
    int b = blockIdx.x, t = threadIdx.x;
    for (int s = t; s < 512; s += 128) yv[s] = ymax[(long)b * 512 + s];
    __syncthreads();
    float acc = 0.f;
    for (int c = 0; c < 512; c++) acc = fmaf(yv[c], We[(long)t * 512 + c], acc);
    emb[t] = acc;
    __syncthreads();
    float acc2 = bh[t];
    for (int ff = 0; ff < 128; ff++) acc2 = fmaf(emb[ff], Wh[(long)t * 128 + ff], acc2);
    out[(long)b * 128 + t] = acc2;
}

// ---------------------------------------------------------------------------
extern "C" void kernel_launch(void* const* d_in, const int* in_sizes, int n_in,
                              void* d_out, int out_size, void* d_ws, size_t ws_size,
                              hipStream_t stream)
{
    const float* x = (const float*)d_in[0];
    const float *W[5], *g[5], *bb[5], *m[5], *v[5];
    for (int li = 0; li < 5; li++) {
        W[li]  = (const float*)d_in[1 + li * 5 + 0];
        g[li]  = (const float*)d_in[1 + li * 5 + 1];
        bb[li] = (const float*)d_in[1 + li * 5 + 2];
        m[li]  = (const float*)d_in[1 + li * 5 + 3];
        v[li]  = (const float*)d_in[1 + li * 5 + 4];
    }
    const float* We = (const float*)d_in[26];
    const float* Wh = (const float*)d_in[27];
    const float* bh = (const float*)d_in[28];
    float* out = (float*)d_out;

    // workspace carve (float units).
    float* ws   = (float*)d_ws;
    float* cat  = ws;                                   // 8,388,608 (B,512,N); stage4 Y reuses
    float* qbuf = cat + (long)8388608;                  // 8,388,608 multi-purpose
    float* pbuf = qbuf + (long)8388608;                 // 4,194,304 (p-values)
    int*   idxb = (int*)(pbuf + 4194304);               // 327,680 ints
    float* xt   = (float*)(idxb + 327680);              // 49,152
    float* xx   = xt + 49152;                           // 16,384
    unsigned short* Wqh = (unsigned short*)(xx + 16384);// 32,768 shorts each
    unsigned short* Wql = Wqh + 32768;
    unsigned short* Wph = Wql + 32768;
    unsigned short* Wpl = Wph + 32768;
    unsigned short* W4h = Wpl + 32768;                  // 262,144 shorts
    unsigned short* W4l = W4h + 262144;
    float* shf  = (float*)(W4l + 262144);               // 512
    float* ymax = shf + 512;                            // 2,048
    // qbuf internal layout:
    //  [0 .. 2,097,152) floats: Ghi/Glo (per-stage bf16 hi/lo, KDP<=128)
    //  [2,097,152 ..): knn slice lists (dead before qv written)
    //  [2,097,152 .. 6,291,456): qv (q-values, point-major)  [after knn]
    //  stage4: whole qbuf = catT hi (16MB) + catT lo (16MB)
    unsigned short* Ghi = (unsigned short*)qbuf;        // 2,097,152 shorts max
    unsigned short* Glo = Ghi + 2097152;
    float* knnd = qbuf + 2097152;                       // 1,310,720 floats
    int*   knni = (int*)(qbuf + 2097152 + 1310720);     // 1,310,720 ints
    float* qv   = qbuf + 2097152;                       // 4,194,304 floats (after knn)
    unsigned short* CTh = (unsigned short*)qbuf;        // 8,388,608 shorts
    unsigned short* CTl = CTh + 8388608;

    // ---- prep ----
    prep_xt_kernel<<<dim3(192), dim3(256), 0, stream>>>(x, xt);

    // ---- stage 0: knn on coords (C=3, K padded to 32) ----
    sqnorm_kernel<<<dim3(16, NB), dim3(256), 0, stream>>>(xt, xx, 3, (long)3 * N_PTS);
    to_bf16_tr<<<dim3(64, NB), dim3(256), 0, stream>>>(
        xt, (long)3 * N_PTS, 3, 32, Ghi, Glo);
    fused_knn_mfma6<32><<<dim3(64, NSL, NB), dim3(256), 0, stream>>>(
        Ghi, Glo, xx, knnd, knni);
    knn_merge4<<<dim3(64), dim3(256), 0, stream>>>(knnd, knni, idxb);
    edge0_kernel<<<dim3(N_PTS / 4, NB), dim3(64, 4), 0, stream>>>(
        xt, idxb, W[0], g[0], bb[0], m[0], v[0], cat);

    // ---- stages 1..3 ----
    const int Cs_[3]   = {64, 64, 128};
    const int co_[3]   = {64, 128, 256};
    const int inO_[3]  = {0, 64, 128};
    const int outO_[3] = {64, 128, 256};
    for (int s = 0; s < 3; s++) {
        int C = Cs_[s], cout = co_[s];
        const float* F = cat + (long)inO_[s] * N_PTS;   // batch stride 512*N
        sqnorm_kernel<<<dim3(16, NB), dim3(256), 0, stream>>>(F, xx, C, (long)512 * N_PTS);
        to_bf16_tr<<<dim3(64, NB), dim3(256), 0, stream>>>(
            F, (long)512 * N_PTS, C, C, Ghi, Glo);
        if (C == 64)
            fused_knn_mfma6<64><<<dim3(64, NSL, NB), dim3(256), 0, stream>>>(
                Ghi, Glo, xx, knnd, knni);
        else
            fused_knn_mfma6<128><<<dim3(64, NSL, NB), dim3(256), 0, stream>>>(
                Ghi, Glo, xx, knnd, knni);
        knn_merge4<<<dim3(64), dim3(256), 0, stream>>>(knnd, knni, idxb);

        int li = s + 1;
        fold_edge_bf16<<<dim3((C * cout + 255) / 256), dim3(256), 0, stream>>>(
            W[li], g[li], bb[li], m[li], v[li], Wqh, Wql, Wph, Wpl, shf, C, cout);
        if (C == 64)
            qp_mfma<64><<<dim3(64, cout / 64, NB), dim3(256), 0, stream>>>(
                Ghi, Glo, Wqh, Wql, Wph, Wpl, shf, qv, pbuf, cout);
        else
            qp_mfma<128><<<dim3(64, cout / 64, NB), dim3(256), 0, stream>>>(
                Ghi, Glo, Wqh, Wql, Wph, Wpl, shf, qv, pbuf, cout);
        gather_max_kernel<<<dim3(N_PTS / 4, NB), dim3(64, 4), 0, stream>>>(
            qv, pbuf, idxb, cat, cout, outO_[s]);
    }

    // ---- stage 4: MFMA pointwise conv + bn + lrelu ----
    fold_plain_bf16<<<dim3((512 * 512 + 255) / 256), dim3(256), 0, stream>>>(
        W[4], g[4], bb[4], m[4], v[4], W4h, W4l, shf, 512, 512);
    to_bf16_tr<<<dim3(64, NB), dim3(256), 0, stream>>>(
        cat, (long)512 * N_PTS, 512, 512, CTh, CTl);
    conv4_mfma<<<dim3(N_PTS / 16, NB), dim3(256), 0, stream>>>(
        CTh, CTl, W4h, W4l, shf, cat);   // Y overwrites dead fp32 cat

    // ---- global max + head ----
    rowmax_kernel<<<dim3(512, NB), dim3(256), 0, stream>>>(cat, ymax);
    head_kernel<<<dim3(NB), dim3(128), 0, stream>>>(ymax, We, Wh, bh, out);
}

// Round 17
// 1208.802 us; speedup vs baseline: 1.1426x; 1.0094x over previous
//
#include <hip/hip_runtime.h>
#include <cfloat>

#define N_PTS 4096
#define NB    4
#define KNN   20
#define EPSB  1e-5f
#define NSL   4          // knn candidate slices per batch-row

typedef short s8v __attribute__((ext_vector_type(8)));
typedef float f4v __attribute__((ext_vector_type(4)));

// ---------------------------------------------------------------------------
// bf16 hi/lo split (round-to-nearest-even both halves)
// ---------------------------------------------------------------------------
__device__ __forceinline__ void bf16split(float x, unsigned short* h, unsigned short* l)
{
    unsigned u = __builtin_bit_cast(unsigned, x);
    unsigned hb = (u + 0x7fffu + ((u >> 16) & 1u)) >> 16;
    float hf = __builtin_bit_cast(float, hb << 16);
    float res = x - hf;
    unsigned u2 = __builtin_bit_cast(unsigned, res);
    unsigned lb = (u2 + 0x7fffu + ((u2 >> 16) & 1u)) >> 16;
    *h = (unsigned short)hb;
    *l = (unsigned short)lb;
}

// ---------------------------------------------------------------------------
// Packed key: fp32 distance (top 24 bits) | 8-bit lane-local ordinal.
// 15 mantissa bits: R10's 11-bit variant FAILED (0.44); this passed (0.03).
// ---------------------------------------------------------------------------
__device__ __forceinline__ unsigned packkey(float d, int lc)
{
    d = fmaxf(d, 0.f);
    unsigned u = __builtin_bit_cast(unsigned, d);
    return (u & 0xFFFFFF00u) | (unsigned)lc;
}

// Branch-free sorted-insert: ascending bubble, 20x (v_min_u32 + v_max_u32).
__device__ __forceinline__ void insert20k(unsigned key, unsigned (&k20)[KNN])
{
#pragma unroll
    for (int j = 0; j < KNN; j++) {
        unsigned old = k20[j];
        unsigned lo = old < key ? old : key;
        key = old < key ? key : old;
        k20[j] = lo;
    }
}

// async global->LDS, 16B per lane; LDS dest = wave-uniform base + lane*16
__device__ __forceinline__ void gl2lds16(const void* g, void* l)
{
    __builtin_amdgcn_global_load_lds(
        (const __attribute__((address_space(1))) unsigned int*)g,
        (__attribute__((address_space(3))) unsigned int*)l,
        16, 0, 0);
}

// 16B-chunk swizzle (involution): chunk g lives at LDS chunk g ^ f(g).
// Spreads the fragment-read bank pattern from 16-way to 2-way (free, m136).
__device__ __forceinline__ int swz(int g)
{
    return g ^ (((g >> 3) ^ (g >> 6)) & 7);
}

// ---------------------------------------------------------------------------
// fp32 -> bf16 hi/lo split, transposed to [b][point][k] (MFMA fragment order).
// grid (N/64, B), block 256 (64 points x 4 k-octets). k >= C zero-filled.
// ---------------------------------------------------------------------------
__global__ __launch_bounds__(256)
void to_bf16_tr(const float* __restrict__ F, long bsF, int C, int KDP,
                unsigned short* __restrict__ Ghi, unsigned short* __restrict__ Glo)
{
    int b = blockIdx.y;
    int n = blockIdx.x * 64 + (threadIdx.x & 63);
    int kq = threadIdx.x >> 6;
    const float* Fb = F + (long)b * bsF;
    for (int k0 = kq * 8; k0 < KDP; k0 += 32) {
        s8v hv, lv;
#pragma unroll
        for (int i = 0; i < 8; i++) {
            int k = k0 + i;
            float x = (k < C) ? Fb[(long)k * N_PTS + n] : 0.f;
            unsigned short h, l;
            bf16split(x, &h, &l);
            hv[i] = (short)h;
            lv[i] = (short)l;
        }
        long o = ((long)b * N_PTS + n) * KDP + k0;
        *(s8v*)&Ghi[o] = hv;
        *(s8v*)&Glo[o] = lv;
    }
}

// ---------------------------------------------------------------------------
// MFMA fused distance + top-20, packed-key in-register selection,
// LDS-staged candidate tiles with XOR bank swizzle (R17).
// grid (N/64, NSL, B), block 256 (4 waves).
// R16 (LDS staging) cut L2 traffic 4x -> 266->164 us, but introduced 16-way
// bank conflicts: fragment read offset n*KDP+quad*8 puts all 16 lanes of a
// quad on one bank quartet (bank independent of n) -> 6.03e7 conflict cycles
// ~= 98 us/CU of the 164 us dispatch. Fix: permute which global 16B chunk
// each staging lane fetches (LDS position is forced to lane index, global
// source is free): chunk g -> LDS chunk swz(g), involution; readers apply
// the same map. Reader bank spread becomes 2-way (free) for all KDP.
// Out: knnd/knni [b][slice][N][KNN] sorted ascending (truncated dist).
// ---------------------------------------------------------------------------
template<int KDP>
__global__ __launch_bounds__(256, 3)
void fused_knn_mfma7(const unsigned short* __restrict__ Ghi,
                     const unsigned short* __restrict__ Glo,
                     const float* __restrict__ xx,
                     float* __restrict__ knnd, int* __restrict__ knni)
{
    constexpr int KS = KDP / 32;
    constexpr int TS = 16 * KDP;          // shorts per tile per array
    constexpr int NCH = (TS * 2) / 16;    // 16B chunks per array per tile
    __shared__ short cbuf[2][2][TS];      // [buf][hi/lo][tile]
    __shared__ unsigned mk[4][16][4][KNN];

    int tid = threadIdx.x;
    int w = tid >> 6, L = tid & 63;
    int n = L & 15;
    int quad = L >> 4;
    int b = blockIdx.z, slice = blockIdx.y;
    int q0 = blockIdx.x * 64, qw = w * 16;
    const unsigned short* Gh = Ghi + (long)b * N_PTS * KDP;
    const unsigned short* Gl = Glo + (long)b * N_PTS * KDP;
    const float* xxb = xx + (long)b * N_PTS;

    // persistent query fragments (global, once)
    s8v qhi[KS], qlo[KS];
    long qbase = (long)(q0 + qw + n) * KDP + quad * 8;
#pragma unroll
    for (int ks = 0; ks < KS; ks++) {
        qhi[ks] = *(const s8v*)&Gh[qbase + ks * 32];
        qlo[ks] = *(const s8v*)&Gl[qbase + ks * 32];
    }
    float xq = xxb[q0 + qw + n];

    unsigned k20[KNN];
#pragma unroll
    for (int j = 0; j < KNN; j++) k20[j] = 0xFFFFFFFFu;

    // swizzled fragment chunk positions (shorts offset = chunk*8)
    int po[KS];
#pragma unroll
    for (int ks = 0; ks < KS; ks++) {
        int gL = n * (KDP / 8) + quad + ks * 4;
        po[ks] = swz(gL) * 8;
    }
    // staging source chunk for this thread (involution)
    int gsrc = swz(tid);

    int w64 = tid & 192;                  // wave base (uniform per wave)
    // prologue: stage tile 0 into buf 0
    {
        long tb = (long)(slice * 1024) * KDP;
        if (tid < NCH) {
            gl2lds16((const char*)(Gh + tb) + gsrc * 16,
                     (char*)&cbuf[0][0][0] + w64 * 16);
            gl2lds16((const char*)(Gl + tb) + gsrc * 16,
                     (char*)&cbuf[0][1][0] + w64 * 16);
        }
    }
    __syncthreads();

    const float* xcp = xxb + slice * 1024 + quad * 4;

    for (int t = 0; t < 64; t++) {
        int cur = t & 1;
        // prefetch tile t+1 into the other buffer (async, no reg round-trip)
        if (t < 63 && tid < NCH) {
            long tb = (long)(slice * 1024 + (t + 1) * 16) * KDP;
            gl2lds16((const char*)(Gh + tb) + gsrc * 16,
                     (char*)&cbuf[cur ^ 1][0][0] + w64 * 16);
            gl2lds16((const char*)(Gl + tb) + gsrc * 16,
                     (char*)&cbuf[cur ^ 1][1][0] + w64 * 16);
        }

        // compute on current tile from LDS (swizzled fragment reads, 2-way)
        const short* Ch = &cbuf[cur][0][0];
        const short* Cl = &cbuf[cur][1][0];
        f4v acc = {0.f, 0.f, 0.f, 0.f};
#pragma unroll
        for (int ks = 0; ks < KS; ks++) {
            s8v chi = *(const s8v*)&Ch[po[ks]];
            s8v clo = *(const s8v*)&Cl[po[ks]];
            acc = __builtin_amdgcn_mfma_f32_16x16x32_bf16(chi, qhi[ks], acc, 0, 0, 0);
            acc = __builtin_amdgcn_mfma_f32_16x16x32_bf16(chi, qlo[ks], acc, 0, 0, 0);
            acc = __builtin_amdgcn_mfma_f32_16x16x32_bf16(clo, qhi[ks], acc, 0, 0, 0);
        }
        float4 xc4 = *(const float4*)xcp;
        float xcv[4] = {xc4.x, xc4.y, xc4.z, xc4.w};
#pragma unroll
        for (int r = 0; r < 4; r++) {
            float d = xq + xcv[r] - 2.f * acc[r];
            insert20k(packkey(d, t * 4 + r), k20);
        }
        xcp += 16;
        __syncthreads();   // drains prefetch (vmcnt) + frees cur buffer
    }

    // publish per-lane lists, then 16 owner lanes merge 4 quad-slices/query
#pragma unroll
    for (int j = 0; j < KNN; j++) mk[w][n][quad][j] = k20[j];
    __syncthreads();
    if (L < 16) {
        int p[4] = {0, 0, 0, 0};
        long o = (((long)b * NSL + slice) * N_PTS + (q0 + qw + L)) * KNN;
#pragma unroll
        for (int j = 0; j < KNN; j++) {
            unsigned bd = 0xFFFFFF00u; int bi = 0x7fffffff; int bq = 0;
#pragma unroll
            for (int qd = 0; qd < 4; qd++) {
                unsigned kk = mk[w][L][qd][p[qd]];
                unsigned db = kk & 0xFFFFFF00u;
                int lc = (int)(kk & 0xFFu);
                int ci = slice * 1024 + (lc >> 2) * 16 + qd * 4 + (lc & 3);
                if (db < bd || (db == bd && ci < bi)) { bd = db; bi = ci; bq = qd; }
            }
            knnd[o + j] = __builtin_bit_cast(float, bd);
            knni[o + j] = bi;
            p[bq]++;
        }
    }
}

// ---------------------------------------------------------------------------
// Merge the NSL sorted slice lists per query -> final idx[b][i][KNN].
// Ties (equal truncated distance) broken by lower global index.
// ---------------------------------------------------------------------------
__global__ void knn_merge4(const float* __restrict__ knnd, const int* __restrict__ knni,
                           int* __restrict__ idxOut)
{
    int id = blockIdx.x * 256 + threadIdx.x;   // b*N + i
    int b = id / N_PTS, i = id % N_PTS;
    const float* dl[NSL]; const int* il[NSL];
#pragma unroll
    for (int qt = 0; qt < NSL; qt++) {
        dl[qt] = knnd + (((long)b * NSL + qt) * N_PTS + i) * KNN;
        il[qt] = knni + (((long)b * NSL + qt) * N_PTS + i) * KNN;
    }
    int p[NSL];
#pragma unroll
    for (int qt = 0; qt < NSL; qt++) p[qt] = 0;
    int* o = idxOut + (long)id * KNN;
#pragma unroll
    for (int j = 0; j < KNN; j++) {
        float best = FLT_MAX; int bi = 0x7fffffff; int bq = 0;
#pragma unroll
        for (int qt = 0; qt < NSL; qt++) {
            float vv = (p[qt] < KNN) ? dl[qt][p[qt]] : FLT_MAX;
            int   ci = (p[qt] < KNN) ? il[qt][p[qt]] : 0x7fffffff;
            if (vv < best || (vv == best && ci < bi)) { best = vv; bi = ci; bq = qt; }
        }
        o[j] = bi;
        p[bq]++;
    }
}

// ---------------------------------------------------------------------------
// Fused q/p MFMA GEMM (edge stages). A = point features (Ghi/Glo, [pt][k]),
// B = folded weights Wq/Wp bf16 hi/lo [cout][C]. Outputs point-major
// qv/pv [b][point][cout]; pv includes +shift.
// grid (N/64, cout/64, B), block 256 (4 waves x 16 points; 4 cout-chunks).
// ---------------------------------------------------------------------------
template<int KDP>
__global__ __launch_bounds__(256)
void qp_mfma(const unsigned short* __restrict__ Ghi,
             const unsigned short* __restrict__ Glo,
             const unsigned short* __restrict__ Wqh, const unsigned short* __restrict__ Wql,
             const unsigned short* __restrict__ Wph, const unsigned short* __restrict__ Wpl,
             const float* __restrict__ shf,
             float* __restrict__ qv, float* __restrict__ pv, int cout)
{
    constexpr int KS = KDP / 32;
    int tid = threadIdx.x;
    int w = tid >> 6, L = tid & 63;
    int n = L & 15, quad = L >> 4;
    int b = blockIdx.z;
    int p0 = blockIdx.x * 64 + w * 16;

    s8v ah[KS], al[KS];
    long abase = ((long)b * N_PTS + p0 + n) * KDP + quad * 8;
#pragma unroll
    for (int ks = 0; ks < KS; ks++) {
        ah[ks] = *(const s8v*)&Ghi[abase + ks * 32];
        al[ks] = *(const s8v*)&Glo[abase + ks * 32];
    }

#pragma unroll
    for (int oc4 = 0; oc4 < 4; oc4++) {
        int oc = blockIdx.y * 4 + oc4;
        long wbase = (long)(oc * 16 + n) * KDP + quad * 8;
        f4v aq = {0.f, 0.f, 0.f, 0.f};
        f4v ap = {0.f, 0.f, 0.f, 0.f};
#pragma unroll
        for (int ks = 0; ks < KS; ks++) {
            s8v wh = *(const s8v*)&Wqh[wbase + ks * 32];
            s8v wl = *(const s8v*)&Wql[wbase + ks * 32];
            aq = __builtin_amdgcn_mfma_f32_16x16x32_bf16(ah[ks], wh, aq, 0, 0, 0);
            aq = __builtin_amdgcn_mfma_f32_16x16x32_bf16(ah[ks], wl, aq, 0, 0, 0);
            aq = __builtin_amdgcn_mfma_f32_16x16x32_bf16(al[ks], wh, aq, 0, 0, 0);
            s8v ph = *(const s8v*)&Wph[wbase + ks * 32];
            s8v pl = *(const s8v*)&Wpl[wbase + ks * 32];
            ap = __builtin_amdgcn_mfma_f32_16x16x32_bf16(ah[ks], ph, ap, 0, 0, 0);
            ap = __builtin_amdgcn_mfma_f32_16x16x32_bf16(ah[ks], pl, ap, 0, 0, 0);
            ap = __builtin_amdgcn_mfma_f32_16x16x32_bf16(al[ks], ph, ap, 0, 0, 0);
        }
        float sv = shf[oc * 16 + n];
#pragma unroll
        for (int r = 0; r < 4; r++) {
            long pt = p0 + quad * 4 + r;
            long o = ((long)b * N_PTS + pt) * cout + oc * 16 + n;
            qv[o] = aq[r];
            pv[o] = ap[r] + sv;
        }
    }
}

// ---------------------------------------------------------------------------
// Stage-4 MFMA conv: Y[b][o][pt] = lrelu(sum_c W4[o][c]*cat[c][pt] + shift[o])
// A = W4 bf16 hi/lo [o][512]; B = catT bf16 hi/lo [b][pt][512].
// grid (N/16, B), block 256: 16 points shared, wave w owns o-chunks w*8..+7.
// ---------------------------------------------------------------------------
__global__ __launch_bounds__(256)
void conv4_mfma(const unsigned short* __restrict__ CTh, const unsigned short* __restrict__ CTl,
                const unsigned short* __restrict__ W4h, const unsigned short* __restrict__ W4l,
                const float* __restrict__ shf, float* __restrict__ Y)
{
    int tid = threadIdx.x;
    int w = tid >> 6, L = tid & 63;
    int n = L & 15, quad = L >> 4;
    int b = blockIdx.y;
    int p0 = blockIdx.x * 16;
    const unsigned short* cth = CTh + ((long)b * N_PTS + p0 + n) * 512 + quad * 8;
    const unsigned short* ctl = CTl + ((long)b * N_PTS + p0 + n) * 512 + quad * 8;

    f4v acc[8];
#pragma unroll
    for (int ch = 0; ch < 8; ch++) acc[ch] = {0.f, 0.f, 0.f, 0.f};

    for (int ks = 0; ks < 16; ks++) {
        s8v bh = *(const s8v*)&cth[ks * 32];
        s8v bl = *(const s8v*)&ctl[ks * 32];
#pragma unroll
        for (int ch = 0; ch < 8; ch++) {
            long o = (long)((w * 8 + ch) * 16 + n) * 512 + quad * 8 + ks * 32;
            s8v ahv = *(const s8v*)&W4h[o];
            s8v alv = *(const s8v*)&W4l[o];
            acc[ch] = __builtin_amdgcn_mfma_f32_16x16x32_bf16(ahv, bh, acc[ch], 0, 0, 0);
            acc[ch] = __builtin_amdgcn_mfma_f32_16x16x32_bf16(ahv, bl, acc[ch], 0, 0, 0);
            acc[ch] = __builtin_amdgcn_mfma_f32_16x16x32_bf16(alv, bh, acc[ch], 0, 0, 0);
        }
    }
#pragma unroll
    for (int ch = 0; ch < 8; ch++) {
#pragma unroll
        for (int r = 0; r < 4; r++) {
            int o = (w * 8 + ch) * 16 + quad * 4 + r;
            float y = acc[ch][r] + shf[o];
            y = y >= 0.f ? y : 0.2f * y;
            Y[((long)b * 512 + o) * N_PTS + p0 + n] = y;
        }
    }
}

// ---------------------------------------------------------------------------
// Weight folding to bf16 hi/lo, [o][c] layout (MFMA B-fragment order).
// ---------------------------------------------------------------------------
__global__ void fold_edge_bf16(const float* __restrict__ W, const float* __restrict__ g,
                               const float* __restrict__ bb, const float* __restrict__ m,
                               const float* __restrict__ v,
                               unsigned short* __restrict__ Wqh, unsigned short* __restrict__ Wql,
                               unsigned short* __restrict__ Wph, unsigned short* __restrict__ Wpl,
                               float* __restrict__ shift, int C, int cout)
{
    int id = blockIdx.x * 256 + threadIdx.x;
    if (id < C * cout) {
        int o = id / C;
        int c = id % C;
        float sc = g[o] * rsqrtf(v[o] + EPSB);
        float wd = W[(long)o * 2 * C + c];
        float wc = W[(long)o * 2 * C + C + c];
        bf16split(sc * wd, &Wqh[id], &Wql[id]);
        bf16split(sc * (wc - wd), &Wph[id], &Wpl[id]);
    }
    if (id < cout) {
        float sc = g[id] * rsqrtf(v[id] + EPSB);
        shift[id] = bb[id] - m[id] * sc;
    }
}

__global__ void fold_plain_bf16(const float* __restrict__ W, const float* __restrict__ g,
                                const float* __restrict__ bb, const float* __restrict__ m,
                                const float* __restrict__ v,
                                unsigned short* __restrict__ W4h, unsigned short* __restrict__ W4l,
                                float* __restrict__ shift, int C, int cout)
{
    int id = blockIdx.x * 256 + threadIdx.x;
    if (id < C * cout) {
        int o = id / C;
        int c = id % C;
        float sc = g[o] * rsqrtf(v[o] + EPSB);
        bf16split(sc * W[(long)o * C + c], &W4h[id], &W4l[id]);
    }
    if (id < cout) {
        float sc = g[id] * rsqrtf(v[id] + EPSB);
        shift[id] = bb[id] - m[id] * sc;
    }
}

// ---------------------------------------------------------------------------
__global__ void prep_xt_kernel(const float* __restrict__ x, float* __restrict__ xt)
{
    int id = blockIdx.x * 256 + threadIdx.x;    // < 4*3*4096
    int b = id / (3 * N_PTS);
    int rem = id % (3 * N_PTS);
    int c = rem / N_PTS;
    int i = rem % N_PTS;
    xt[id] = x[((long)b * N_PTS + i) * 3 + c];
}

__global__ void sqnorm_kernel(const float* __restrict__ F, float* __restrict__ xx,
                              int C, long bsF)
{
    int b = blockIdx.y;
    int j = blockIdx.x * 256 + threadIdx.x;
    const float* f = F + (long)b * bsF;
    float s = 0.f;
    for (int c = 0; c < C; c++) {
        float t = f[(long)c * N_PTS + j];
        s = fmaf(t, t, s);
    }
    xx[(long)b * N_PTS + j] = s;
}

__global__ void gather_max_kernel(const float* __restrict__ q, const float* __restrict__ p,
                                  const int* __restrict__ idx, float* __restrict__ cat,
                                  int cout, int c_off)
{
    int b = blockIdx.y;
    int i = blockIdx.x * 4 + threadIdx.y;
    int tx = threadIdx.x;
    const int* ip = idx + ((long)b * N_PTS + i) * KNN;
    int js[KNN];
#pragma unroll
    for (int k = 0; k < KNN; k++) js[k] = ip[k];
    const float* qb = q + (long)b * N_PTS * cout;
    const float* pb = p + ((long)b * N_PTS + i) * cout;
    float* ob = cat + ((long)b * 512 + c_off) * N_PTS + i;
    for (int o0 = 0; o0 < cout; o0 += 64) {
        int o = o0 + tx;
        float pv = pb[o];
        float mx = -FLT_MAX;
#pragma unroll
        for (int k = 0; k < KNN; k++) {
            float val = qb[(long)js[k] * cout + o] + pv;
            val = val >= 0.f ? val : 0.2f * val;
            mx = fmaxf(mx, val);
        }
        ob[(long)o * N_PTS] = mx;
    }
}

__global__ void edge0_kernel(const float* __restrict__ xt, const int* __restrict__ idx,
                             const float* __restrict__ W0, const float* __restrict__ g0,
                             const float* __restrict__ b0, const float* __restrict__ m0,
                             const float* __restrict__ v0, float* __restrict__ cat)
{
    int b = blockIdx.y;
    int i = blockIdx.x * 4 + threadIdx.y;
    int o = threadIdx.x;
    const float* xb = xt + (long)b * 3 * N_PTS;
    float cx = xb[i], cy = xb[N_PTS + i], cz = xb[2 * N_PTS + i];
    float w[9];
#pragma unroll
    for (int c = 0; c < 9; c++) w[c] = W0[o * 9 + c];
    float sc = g0[o] * rsqrtf(v0[o] + EPSB);
    float sh = b0[o] - m0[o] * sc;
    const int* ip = idx + ((long)b * N_PTS + i) * KNN;
    float mx = -FLT_MAX;
#pragma unroll
    for (int k = 0; k < KNN; k++) {
        int j = ip[k];
        float nx = xb[j], ny = xb[N_PTS + j], nz = xb[2 * N_PTS + j];
        float dx = nx - cx, dy = ny - cy, dz = nz - cz;
        float crx = cy * nz - cz * ny;
        float cry = cz * nx - cx * nz;
        float crz = cx * ny - cy * nx;
        float y = w[0] * dx + w[1] * dy + w[2] * dz
                + w[3] * crx + w[4] * cry + w[5] * crz
                + w[6] * cx + w[7] * cy + w[8] * cz;
        y = y * sc + sh;
        y = y >= 0.f ? y : 0.2f * y;
        mx = fmaxf(mx, y);
    }
    cat[((long)b * 512 + o) * N_PTS + i] = mx;
}

__global__ void rowmax_kernel(const float* __restrict__ Y, float* __restrict__ ymax)
{
    __shared__ float red[256];
    int b = blockIdx.y, o = blockIdx.x, t = threadIdx.x;
    const float* yb = Y + ((long)b * 512 + o) * N_PTS;
    float mx = -FLT_MAX;
#pragma unroll
    for (int s = 0; s < N_PTS / 256; s++) mx = fmaxf(mx, yb[t + 256 * s]);
    red[t] = mx;
    __syncthreads();
    for (int off = 128; off > 0; off >>= 1) {
        if (t < off) red[t] = fmaxf(red[t], red[t + off]);
        __syncthreads();
    }
    if (t == 0) ymax[(long)b * 512 + o] = red[0];
}

__global__ void head_kernel(const float* __restrict__ ymax, const float* __restrict__ We,
                            const float* __restrict__ Wh, const float* __restrict__ bh,
                            float* __restrict__ out)
{
    __shared__ float emb[128];
    __shared__ float yv[512];
    int b = blockIdx.x, t = threadIdx.x;
    for (int s = t; s < 512; s += 128) yv[s] = ymax[(long)b * 512 + s];
    __syncthreads();
    float acc = 0.f;
    for (int c = 0; c < 512; c++) acc = fmaf(yv[c], We[(long)t * 512 + c], acc);
    emb[t] = acc;
    __syncthreads();
    float acc2 = bh[t];
    for (int ff = 0; ff < 128; ff++) acc2 = fmaf(emb[ff], Wh[(long)t * 128 + ff], acc2);
    out[(long)b * 128 + t] = acc2;
}

// ---------------------------------------------------------------------------
extern "C" void kernel_launch(void* const* d_in, const int* in_sizes, int n_in,
                              void* d_out, int out_size, void* d_ws, size_t ws_size,
                              hipStream_t stream)
{
    const float* x = (const float*)d_in[0];
    const float *W[5], *g[5], *bb[5], *m[5], *v[5];
    for (int li = 0; li < 5; li++) {
        W[li]  = (const float*)d_in[1 + li * 5 + 0];
        g[li]  = (const float*)d_in[1 + li * 5 + 1];
        bb[li] = (const float*)d_in[1 + li * 5 + 2];
        m[li]  = (const float*)d_in[1 + li * 5 + 3];
        v[li]  = (const float*)d_in[1 + li * 5 + 4];
    }
    const float* We = (const float*)d_in[26];
    const float* Wh = (const float*)d_in[27];
    const float* bh = (const float*)d_in[28];
    float* out = (float*)d_out;

    // workspace carve (float units).
    float* ws   = (float*)d_ws;
    float* cat  = ws;                                   // 8,388,608 (B,512,N); stage4 Y reuses
    float* qbuf = cat + (long)8388608;                  // 8,388,608 multi-purpose
    float* pbuf = qbuf + (long)8388608;                 // 4,194,304 (p-values)
    int*   idxb = (int*)(pbuf + 4194304);               // 327,680 ints
    float* xt   = (float*)(idxb + 327680);              // 49,152
    float* xx   = xt + 49152;                           // 16,384
    unsigned short* Wqh = (unsigned short*)(xx + 16384);// 32,768 shorts each
    unsigned short* Wql = Wqh + 32768;
    unsigned short* Wph = Wql + 32768;
    unsigned short* Wpl = Wph + 32768;
    unsigned short* W4h = Wpl + 32768;                  // 262,144 shorts
    unsigned short* W4l = W4h + 262144;
    float* shf  = (float*)(W4l + 262144);               // 512
    float* ymax = shf + 512;                            // 2,048
    // qbuf internal layout:
    //  [0 .. 2,097,152) floats: Ghi/Glo (per-stage bf16 hi/lo, KDP<=128)
    //  [2,097,152 ..): knn slice lists (dead before qv written)
    //  [2,097,152 .. 6,291,456): qv (q-values, point-major)  [after knn]
    //  stage4: whole qbuf = catT hi (16MB) + catT lo (16MB)
    unsigned short* Ghi = (unsigned short*)qbuf;        // 2,097,152 shorts max
    unsigned short* Glo = Ghi + 2097152;
    float* knnd = qbuf + 2097152;                       // 1,310,720 floats
    int*   knni = (int*)(qbuf + 2097152 + 1310720);     // 1,310,720 ints
    float* qv   = qbuf + 2097152;                       // 4,194,304 floats (after knn)
    unsigned short* CTh = (unsigned short*)qbuf;        // 8,388,608 shorts
    unsigned short* CTl = CTh + 8388608;

    // ---- prep ----
    prep_xt_kernel<<<dim3(192), dim3(256), 0, stream>>>(x, xt);

    // ---- stage 0: knn on coords (C=3, K padded to 32) ----
    sqnorm_kernel<<<dim3(16, NB), dim3(256), 0, stream>>>(xt, xx, 3, (long)3 * N_PTS);
    to_bf16_tr<<<dim3(64, NB), dim3(256), 0, stream>>>(
        xt, (long)3 * N_PTS, 3, 32, Ghi, Glo);
    fused_knn_mfma7<32><<<dim3(64, NSL, NB), dim3(256), 0, stream>>>(
        Ghi, Glo, xx, knnd, knni);
    knn_merge4<<<dim3(64), dim3(256), 0, stream>>>(knnd, knni, idxb);
    edge0_kernel<<<dim3(N_PTS / 4, NB), dim3(64, 4), 0, stream>>>(
        xt, idxb, W[0], g[0], bb[0], m[0], v[0], cat);

    // ---- stages 1..3 ----
    const int Cs_[3]   = {64, 64, 128};
    const int co_[3]   = {64, 128, 256};
    const int inO_[3]  = {0, 64, 128};
    const int outO_[3] = {64, 128, 256};
    for (int s = 0; s < 3; s++) {
        int C = Cs_[s], cout = co_[s];
        const float* F = cat + (long)inO_[s] * N_PTS;   // batch stride 512*N
        sqnorm_kernel<<<dim3(16, NB), dim3(256), 0, stream>>>(F, xx, C, (long)512 * N_PTS);
        to_bf16_tr<<<dim3(64, NB), dim3(256), 0, stream>>>(
            F, (long)512 * N_PTS, C, C, Ghi, Glo);
        if (C == 64)
            fused_knn_mfma7<64><<<dim3(64, NSL, NB), dim3(256), 0, stream>>>(
                Ghi, Glo, xx, knnd, knni);
        else
            fused_knn_mfma7<128><<<dim3(64, NSL, NB), dim3(256), 0, stream>>>(
                Ghi, Glo, xx, knnd, knni);
        knn_merge4<<<dim3(64), dim3(256), 0, stream>>>(knnd, knni, idxb);

        int li = s + 1;
        fold_edge_bf16<<<dim3((C * cout + 255) / 256), dim3(256), 0, stream>>>(
            W[li], g[li], bb[li], m[li], v[li], Wqh, Wql, Wph, Wpl, shf, C, cout);
        if (C == 64)
            qp_mfma<64><<<dim3(64, cout / 64, NB), dim3(256), 0, stream>>>(
                Ghi, Glo, Wqh, Wql, Wph, Wpl, shf, qv, pbuf, cout);
        else
            qp_mfma<128><<<dim3(64, cout / 64, NB), dim3(256), 0, stream>>>(
                Ghi, Glo, Wqh, Wql, Wph, Wpl, shf, qv, pbuf, cout);
        gather_max_kernel<<<dim3(N_PTS / 4, NB), dim3(64, 4), 0, stream>>>(
            qv, pbuf, idxb, cat, cout, outO_[s]);
    }

    // ---- stage 4: MFMA pointwise conv + bn + lrelu ----
    fold_plain_bf16<<<dim3((512 * 512 + 255) / 256), dim3(256), 0, stream>>>(
        W[4], g[4], bb[4], m[4], v[4], W4h, W4l, shf, 512, 512);
    to_bf16_tr<<<dim3(64, NB), dim3(256), 0, stream>>>(
        cat, (long)512 * N_PTS, 512, 512, CTh, CTl);
    conv4_mfma<<<dim3(N_PTS / 16, NB), dim3(256), 0, stream>>>(
        CTh, CTl, W4h, W4l, shf, cat);   // Y overwrites dead fp32 cat

    // ---- global max + head ----
    rowmax_kernel<<<dim3(512, NB), dim3(256), 0, stream>>>(cat, ymax);
    head_kernel<<<dim3(NB), dim3(128), 0, stream>>>(ymax, We, Wh, bh, out);
}

// Round 18
// 1096.595 us; speedup vs baseline: 1.2596x; 1.1023x over previous
//
#include <hip/hip_runtime.h>
#include <cfloat>

#define N_PTS 4096
#define NB    4
#define KNN   20
#define EPSB  1e-5f
#define NSL   4          // knn candidate slices per batch-row

typedef short s8v __attribute__((ext_vector_type(8)));
typedef float f4v __attribute__((ext_vector_type(4)));

// ---------------------------------------------------------------------------
// bf16 hi/lo split (round-to-nearest-even both halves)
// ---------------------------------------------------------------------------
__device__ __forceinline__ void bf16split(float x, unsigned short* h, unsigned short* l)
{
    unsigned u = __builtin_bit_cast(unsigned, x);
    unsigned hb = (u + 0x7fffu + ((u >> 16) & 1u)) >> 16;
    float hf = __builtin_bit_cast(float, hb << 16);
    float res = x - hf;
    unsigned u2 = __builtin_bit_cast(unsigned, res);
    unsigned lb = (u2 + 0x7fffu + ((u2 >> 16) & 1u)) >> 16;
    *h = (unsigned short)hb;
    *l = (unsigned short)lb;
}

// ---------------------------------------------------------------------------
// Packed key: fp32 distance (top 24 bits) | 8-bit lane-local ordinal.
// 15 mantissa bits: R10's 11-bit variant FAILED (0.44); this passed (0.03).
// ---------------------------------------------------------------------------
__device__ __forceinline__ unsigned packkey(float d, int lc)
{
    d = fmaxf(d, 0.f);
    unsigned u = __builtin_bit_cast(unsigned, d);
    return (u & 0xFFFFFF00u) | (unsigned)lc;
}

// Branch-free sorted-insert: ascending bubble, 20x (v_min_u32 + v_max_u32).
__device__ __forceinline__ void insert20k(unsigned key, unsigned (&k20)[KNN])
{
#pragma unroll
    for (int j = 0; j < KNN; j++) {
        unsigned old = k20[j];
        unsigned lo = old < key ? old : key;
        key = old < key ? key : old;
        k20[j] = lo;
    }
}

// async global->LDS, 16B per lane; LDS dest = wave-uniform base + lane*16
__device__ __forceinline__ void gl2lds16(const void* g, void* l)
{
    __builtin_amdgcn_global_load_lds(
        (const __attribute__((address_space(1))) unsigned int*)g,
        (__attribute__((address_space(3))) unsigned int*)l,
        16, 0, 0);
}

// 16B-chunk swizzle (involution): chunk g lives at LDS chunk g ^ f(g).
// Spreads the fragment-read bank pattern from 16-way to 2-way.
__device__ __forceinline__ int swz(int g)
{
    return g ^ (((g >> 3) ^ (g >> 6)) & 7);
}

// ---------------------------------------------------------------------------
// Point-major fp32 -> bf16 hi/lo, [b][point][k] output (MFMA fragment order).
// Input F point-major: row = F + b*bsF + n*ldF, C valid channels, zero-pad
// to KDP. Pure row copy+convert: every lane streams its own contiguous row.
// grid (N/64, B), block 256 (64 points x 4 k-octets).
// ---------------------------------------------------------------------------
__global__ __launch_bounds__(256)
void to_bf16_pm(const float* __restrict__ F, long bsF, int ldF, int C, int KDP,
                unsigned short* __restrict__ Ghi, unsigned short* __restrict__ Glo)
{
    int b = blockIdx.y;
    int n = blockIdx.x * 64 + (threadIdx.x & 63);
    int kq = threadIdx.x >> 6;
    const float* Fr = F + (long)b * bsF + (long)n * ldF;
    for (int k0 = kq * 8; k0 < KDP; k0 += 32) {
        s8v hv, lv;
#pragma unroll
        for (int i = 0; i < 8; i++) {
            int k = k0 + i;
            float x = (k < C) ? Fr[k] : 0.f;
            unsigned short h, l;
            bf16split(x, &h, &l);
            hv[i] = (short)h;
            lv[i] = (short)l;
        }
        long o = ((long)b * N_PTS + n) * KDP + k0;
        *(s8v*)&Ghi[o] = hv;
        *(s8v*)&Glo[o] = lv;
    }
}

// ---------------------------------------------------------------------------
// Point-major squared norms: xx[b][i] = sum_c row[c]^2
// ---------------------------------------------------------------------------
__global__ void sqnorm_pm(const float* __restrict__ F, float* __restrict__ xx,
                          int C, int ldF, long bsF)
{
    int b = blockIdx.y;
    int i = blockIdx.x * 256 + threadIdx.x;
    const float* r = F + (long)b * bsF + (long)i * ldF;
    float s = 0.f;
    for (int c = 0; c < C; c++) s = fmaf(r[c], r[c], s);
    xx[(long)b * N_PTS + i] = s;
}

// ---------------------------------------------------------------------------
// MFMA fused distance + top-20, packed-key in-register selection,
// LDS-staged candidate tiles with XOR bank swizzle (R17 kernel, unchanged).
// ---------------------------------------------------------------------------
template<int KDP>
__global__ __launch_bounds__(256, 3)
void fused_knn_mfma7(const unsigned short* __restrict__ Ghi,
                     const unsigned short* __restrict__ Glo,
                     const float* __restrict__ xx,
                     float* __restrict__ knnd, int* __restrict__ knni)
{
    constexpr int KS = KDP / 32;
    constexpr int TS = 16 * KDP;          // shorts per tile per array
    constexpr int NCH = (TS * 2) / 16;    // 16B chunks per array per tile
    __shared__ short cbuf[2][2][TS];      // [buf][hi/lo][tile]
    __shared__ unsigned mk[4][16][4][KNN];

    int tid = threadIdx.x;
    int w = tid >> 6, L = tid & 63;
    int n = L & 15;
    int quad = L >> 4;
    int b = blockIdx.z, slice = blockIdx.y;
    int q0 = blockIdx.x * 64, qw = w * 16;
    const unsigned short* Gh = Ghi + (long)b * N_PTS * KDP;
    const unsigned short* Gl = Glo + (long)b * N_PTS * KDP;
    const float* xxb = xx + (long)b * N_PTS;

    // persistent query fragments (global, once)
    s8v qhi[KS], qlo[KS];
    long qbase = (long)(q0 + qw + n) * KDP + quad * 8;
#pragma unroll
    for (int ks = 0; ks < KS; ks++) {
        qhi[ks] = *(const s8v*)&Gh[qbase + ks * 32];
        qlo[ks] = *(const s8v*)&Gl[qbase + ks * 32];
    }
    float xq = xxb[q0 + qw + n];

    unsigned k20[KNN];
#pragma unroll
    for (int j = 0; j < KNN; j++) k20[j] = 0xFFFFFFFFu;

    // swizzled fragment chunk positions (shorts offset = chunk*8)
    int po[KS];
#pragma unroll
    for (int ks = 0; ks < KS; ks++) {
        int gL = n * (KDP / 8) + quad + ks * 4;
        po[ks] = swz(gL) * 8;
    }
    int gsrc = swz(tid);                  // staging source chunk (involution)

    int w64 = tid & 192;                  // wave base (uniform per wave)
    {
        long tb = (long)(slice * 1024) * KDP;
        if (tid < NCH) {
            gl2lds16((const char*)(Gh + tb) + gsrc * 16,
                     (char*)&cbuf[0][0][0] + w64 * 16);
            gl2lds16((const char*)(Gl + tb) + gsrc * 16,
                     (char*)&cbuf[0][1][0] + w64 * 16);
        }
    }
    __syncthreads();

    const float* xcp = xxb + slice * 1024 + quad * 4;

    for (int t = 0; t < 64; t++) {
        int cur = t & 1;
        if (t < 63 && tid < NCH) {
            long tb = (long)(slice * 1024 + (t + 1) * 16) * KDP;
            gl2lds16((const char*)(Gh + tb) + gsrc * 16,
                     (char*)&cbuf[cur ^ 1][0][0] + w64 * 16);
            gl2lds16((const char*)(Gl + tb) + gsrc * 16,
                     (char*)&cbuf[cur ^ 1][1][0] + w64 * 16);
        }

        const short* Ch = &cbuf[cur][0][0];
        const short* Cl = &cbuf[cur][1][0];
        f4v acc = {0.f, 0.f, 0.f, 0.f};
#pragma unroll
        for (int ks = 0; ks < KS; ks++) {
            s8v chi = *(const s8v*)&Ch[po[ks]];
            s8v clo = *(const s8v*)&Cl[po[ks]];
            acc = __builtin_amdgcn_mfma_f32_16x16x32_bf16(chi, qhi[ks], acc, 0, 0, 0);
            acc = __builtin_amdgcn_mfma_f32_16x16x32_bf16(chi, qlo[ks], acc, 0, 0, 0);
            acc = __builtin_amdgcn_mfma_f32_16x16x32_bf16(clo, qhi[ks], acc, 0, 0, 0);
        }
        float4 xc4 = *(const float4*)xcp;
        float xcv[4] = {xc4.x, xc4.y, xc4.z, xc4.w};
#pragma unroll
        for (int r = 0; r < 4; r++) {
            float d = xq + xcv[r] - 2.f * acc[r];
            insert20k(packkey(d, t * 4 + r), k20);
        }
        xcp += 16;
        __syncthreads();
    }

#pragma unroll
    for (int j = 0; j < KNN; j++) mk[w][n][quad][j] = k20[j];
    __syncthreads();
    if (L < 16) {
        int p[4] = {0, 0, 0, 0};
        long o = (((long)b * NSL + slice) * N_PTS + (q0 + qw + L)) * KNN;
#pragma unroll
        for (int j = 0; j < KNN; j++) {
            unsigned bd = 0xFFFFFF00u; int bi = 0x7fffffff; int bq = 0;
#pragma unroll
            for (int qd = 0; qd < 4; qd++) {
                unsigned kk = mk[w][L][qd][p[qd]];
                unsigned db = kk & 0xFFFFFF00u;
                int lc = (int)(kk & 0xFFu);
                int ci = slice * 1024 + (lc >> 2) * 16 + qd * 4 + (lc & 3);
                if (db < bd || (db == bd && ci < bi)) { bd = db; bi = ci; bq = qd; }
            }
            knnd[o + j] = __builtin_bit_cast(float, bd);
            knni[o + j] = bi;
            p[bq]++;
        }
    }
}

// ---------------------------------------------------------------------------
// Merge the NSL sorted slice lists per query -> final idx[b][i][KNN].
// ---------------------------------------------------------------------------
__global__ void knn_merge4(const float* __restrict__ knnd, const int* __restrict__ knni,
                           int* __restrict__ idxOut)
{
    int id = blockIdx.x * 256 + threadIdx.x;   // b*N + i
    int b = id / N_PTS, i = id % N_PTS;
    const float* dl[NSL]; const int* il[NSL];
#pragma unroll
    for (int qt = 0; qt < NSL; qt++) {
        dl[qt] = knnd + (((long)b * NSL + qt) * N_PTS + i) * KNN;
        il[qt] = knni + (((long)b * NSL + qt) * N_PTS + i) * KNN;
    }
    int p[NSL];
#pragma unroll
    for (int qt = 0; qt < NSL; qt++) p[qt] = 0;
    int* o = idxOut + (long)id * KNN;
#pragma unroll
    for (int j = 0; j < KNN; j++) {
        float best = FLT_MAX; int bi = 0x7fffffff; int bq = 0;
#pragma unroll
        for (int qt = 0; qt < NSL; qt++) {
            float vv = (p[qt] < KNN) ? dl[qt][p[qt]] : FLT_MAX;
            int   ci = (p[qt] < KNN) ? il[qt][p[qt]] : 0x7fffffff;
            if (vv < best || (vv == best && ci < bi)) { best = vv; bi = ci; bq = qt; }
        }
        o[j] = bi;
        p[bq]++;
    }
}

// ---------------------------------------------------------------------------
// Fused q/p MFMA GEMM (edge stages) — unchanged from R17.
// ---------------------------------------------------------------------------
template<int KDP>
__global__ __launch_bounds__(256)
void qp_mfma(const unsigned short* __restrict__ Ghi,
             const unsigned short* __restrict__ Glo,
             const unsigned short* __restrict__ Wqh, const unsigned short* __restrict__ Wql,
             const unsigned short* __restrict__ Wph, const unsigned short* __restrict__ Wpl,
             const float* __restrict__ shf,
             float* __restrict__ qv, float* __restrict__ pv, int cout)
{
    constexpr int KS = KDP / 32;
    int tid = threadIdx.x;
    int w = tid >> 6, L = tid & 63;
    int n = L & 15, quad = L >> 4;
    int b = blockIdx.z;
    int p0 = blockIdx.x * 64 + w * 16;

    s8v ah[KS], al[KS];
    long abase = ((long)b * N_PTS + p0 + n) * KDP + quad * 8;
#pragma unroll
    for (int ks = 0; ks < KS; ks++) {
        ah[ks] = *(const s8v*)&Ghi[abase + ks * 32];
        al[ks] = *(const s8v*)&Glo[abase + ks * 32];
    }

#pragma unroll
    for (int oc4 = 0; oc4 < 4; oc4++) {
        int oc = blockIdx.y * 4 + oc4;
        long wbase = (long)(oc * 16 + n) * KDP + quad * 8;
        f4v aq = {0.f, 0.f, 0.f, 0.f};
        f4v ap = {0.f, 0.f, 0.f, 0.f};
#pragma unroll
        for (int ks = 0; ks < KS; ks++) {
            s8v wh = *(const s8v*)&Wqh[wbase + ks * 32];
            s8v wl = *(const s8v*)&Wql[wbase + ks * 32];
            aq = __builtin_amdgcn_mfma_f32_16x16x32_bf16(ah[ks], wh, aq, 0, 0, 0);
            aq = __builtin_amdgcn_mfma_f32_16x16x32_bf16(ah[ks], wl, aq, 0, 0, 0);
            aq = __builtin_amdgcn_mfma_f32_16x16x32_bf16(al[ks], wh, aq, 0, 0, 0);
            s8v ph = *(const s8v*)&Wph[wbase + ks * 32];
            s8v pl = *(const s8v*)&Wpl[wbase + ks * 32];
            ap = __builtin_amdgcn_mfma_f32_16x16x32_bf16(ah[ks], ph, ap, 0, 0, 0);
            ap = __builtin_amdgcn_mfma_f32_16x16x32_bf16(ah[ks], pl, ap, 0, 0, 0);
            ap = __builtin_amdgcn_mfma_f32_16x16x32_bf16(al[ks], ph, ap, 0, 0, 0);
        }
        float sv = shf[oc * 16 + n];
#pragma unroll
        for (int r = 0; r < 4; r++) {
            long pt = p0 + quad * 4 + r;
            long o = ((long)b * N_PTS + pt) * cout + oc * 16 + n;
            qv[o] = aq[r];
            pv[o] = ap[r] + sv;
        }
    }
}

// ---------------------------------------------------------------------------
// Stage-4 MFMA conv — unchanged (Y written channel-major for rowmax).
// ---------------------------------------------------------------------------
__global__ __launch_bounds__(256)
void conv4_mfma(const unsigned short* __restrict__ CTh, const unsigned short* __restrict__ CTl,
                const unsigned short* __restrict__ W4h, const unsigned short* __restrict__ W4l,
                const float* __restrict__ shf, float* __restrict__ Y)
{
    int tid = threadIdx.x;
    int w = tid >> 6, L = tid & 63;
    int n = L & 15, quad = L >> 4;
    int b = blockIdx.y;
    int p0 = blockIdx.x * 16;
    const unsigned short* cth = CTh + ((long)b * N_PTS + p0 + n) * 512 + quad * 8;
    const unsigned short* ctl = CTl + ((long)b * N_PTS + p0 + n) * 512 + quad * 8;

    f4v acc[8];
#pragma unroll
    for (int ch = 0; ch < 8; ch++) acc[ch] = {0.f, 0.f, 0.f, 0.f};

    for (int ks = 0; ks < 16; ks++) {
        s8v bh = *(const s8v*)&cth[ks * 32];
        s8v bl = *(const s8v*)&ctl[ks * 32];
#pragma unroll
        for (int ch = 0; ch < 8; ch++) {
            long o = (long)((w * 8 + ch) * 16 + n) * 512 + quad * 8 + ks * 32;
            s8v ahv = *(const s8v*)&W4h[o];
            s8v alv = *(const s8v*)&W4l[o];
            acc[ch] = __builtin_amdgcn_mfma_f32_16x16x32_bf16(ahv, bh, acc[ch], 0, 0, 0);
            acc[ch] = __builtin_amdgcn_mfma_f32_16x16x32_bf16(ahv, bl, acc[ch], 0, 0, 0);
            acc[ch] = __builtin_amdgcn_mfma_f32_16x16x32_bf16(alv, bh, acc[ch], 0, 0, 0);
        }
    }
#pragma unroll
    for (int ch = 0; ch < 8; ch++) {
#pragma unroll
        for (int r = 0; r < 4; r++) {
            int o = (w * 8 + ch) * 16 + quad * 4 + r;
            float y = acc[ch][r] + shf[o];
            y = y >= 0.f ? y : 0.2f * y;
            Y[((long)b * 512 + o) * N_PTS + p0 + n] = y;
        }
    }
}

// ---------------------------------------------------------------------------
// Weight folding to bf16 hi/lo, [o][c] layout (MFMA B-fragment order).
// ---------------------------------------------------------------------------
__global__ void fold_edge_bf16(const float* __restrict__ W, const float* __restrict__ g,
                               const float* __restrict__ bb, const float* __restrict__ m,
                               const float* __restrict__ v,
                               unsigned short* __restrict__ Wqh, unsigned short* __restrict__ Wql,
                               unsigned short* __restrict__ Wph, unsigned short* __restrict__ Wpl,
                               float* __restrict__ shift, int C, int cout)
{
    int id = blockIdx.x * 256 + threadIdx.x;
    if (id < C * cout) {
        int o = id / C;
        int c = id % C;
        float sc = g[o] * rsqrtf(v[o] + EPSB);
        float wd = W[(long)o * 2 * C + c];
        float wc = W[(long)o * 2 * C + C + c];
        bf16split(sc * wd, &Wqh[id], &Wql[id]);
        bf16split(sc * (wc - wd), &Wph[id], &Wpl[id]);
    }
    if (id < cout) {
        float sc = g[id] * rsqrtf(v[id] + EPSB);
        shift[id] = bb[id] - m[id] * sc;
    }
}

__global__ void fold_plain_bf16(const float* __restrict__ W, const float* __restrict__ g,
                                const float* __restrict__ bb, const float* __restrict__ m,
                                const float* __restrict__ v,
                                unsigned short* __restrict__ W4h, unsigned short* __restrict__ W4l,
                                float* __restrict__ shift, int C, int cout)
{
    int id = blockIdx.x * 256 + threadIdx.x;
    if (id < C * cout) {
        int o = id / C;
        int c = id % C;
        float sc = g[o] * rsqrtf(v[o] + EPSB);
        bf16split(sc * W[(long)o * C + c], &W4h[id], &W4l[id]);
    }
    if (id < cout) {
        float sc = g[id] * rsqrtf(v[id] + EPSB);
        shift[id] = bb[id] - m[id] * sc;
    }
}

// ---------------------------------------------------------------------------
// Gather+max with POINT-MAJOR cat output (coalesced writes).
// grid (N/4, B), block (64,4): wave = one point, lanes = channels.
// ---------------------------------------------------------------------------
__global__ void gather_max_pm(const float* __restrict__ q, const float* __restrict__ p,
                              const int* __restrict__ idx, float* __restrict__ cat,
                              int cout, int c_off)
{
    int b = blockIdx.y;
    int i = blockIdx.x * 4 + threadIdx.y;
    int tx = threadIdx.x;
    const int* ip = idx + ((long)b * N_PTS + i) * KNN;
    int js[KNN];
#pragma unroll
    for (int k = 0; k < KNN; k++) js[k] = ip[k];
    const float* qb = q + (long)b * N_PTS * cout;
    const float* pb = p + ((long)b * N_PTS + i) * cout;
    float* ob = cat + ((long)b * N_PTS + i) * 512 + c_off;
    for (int o0 = 0; o0 < cout; o0 += 64) {
        int o = o0 + tx;
        float pv = pb[o];
        float mx = -FLT_MAX;
#pragma unroll
        for (int k = 0; k < KNN; k++) {
            float val = qb[(long)js[k] * cout + o] + pv;
            val = val >= 0.f ? val : 0.2f * val;
            mx = fmaxf(mx, val);
        }
        ob[o] = mx;          // coalesced: lanes write consecutive channels
    }
}

// ---------------------------------------------------------------------------
// Block 0 edge conv, point-major x input and point-major cat output.
// grid (N/4, B), block (64,4): wave = one point, lanes = 64 channels.
// Neighbor reads are 3 consecutive floats (1 line) broadcast across the wave.
// ---------------------------------------------------------------------------
__global__ void edge0_pm(const float* __restrict__ x, const int* __restrict__ idx,
                         const float* __restrict__ W0, const float* __restrict__ g0,
                         const float* __restrict__ b0, const float* __restrict__ m0,
                         const float* __restrict__ v0, float* __restrict__ cat)
{
    int b = blockIdx.y;
    int i = blockIdx.x * 4 + threadIdx.y;
    int o = threadIdx.x;
    const float* xc = x + ((long)b * N_PTS + i) * 3;
    float cx = xc[0], cy = xc[1], cz = xc[2];
    float w[9];
#pragma unroll
    for (int c = 0; c < 9; c++) w[c] = W0[o * 9 + c];
    float sc = g0[o] * rsqrtf(v0[o] + EPSB);
    float sh = b0[o] - m0[o] * sc;
    const int* ip = idx + ((long)b * N_PTS + i) * KNN;
    float mx = -FLT_MAX;
#pragma unroll
    for (int k = 0; k < KNN; k++) {
        const float* xn = x + ((long)b * N_PTS + ip[k]) * 3;
        float nx = xn[0], ny = xn[1], nz = xn[2];
        float dx = nx - cx, dy = ny - cy, dz = nz - cz;
        float crx = cy * nz - cz * ny;
        float cry = cz * nx - cx * nz;
        float crz = cx * ny - cy * nx;
        float y = w[0] * dx + w[1] * dy + w[2] * dz
                + w[3] * crx + w[4] * cry + w[5] * crz
                + w[6] * cx + w[7] * cy + w[8] * cz;
        y = y * sc + sh;
        y = y >= 0.f ? y : 0.2f * y;
        mx = fmaxf(mx, y);
    }
    cat[((long)b * N_PTS + i) * 512 + o] = mx;   // coalesced
}

__global__ void rowmax_kernel(const float* __restrict__ Y, float* __restrict__ ymax)
{
    __shared__ float red[256];
    int b = blockIdx.y, o = blockIdx.x, t = threadIdx.x;
    const float* yb = Y + ((long)b * 512 + o) * N_PTS;
    float mx = -FLT_MAX;
#pragma unroll
    for (int s = 0; s < N_PTS / 256; s++) mx = fmaxf(mx, yb[t + 256 * s]);
    red[t] = mx;
    __syncthreads();
    for (int off = 128; off > 0; off >>= 1) {
        if (t < off) red[t] = fmaxf(red[t], red[t + off]);
        __syncthreads();
    }
    if (t == 0) ymax[(long)b * 512 + o] = red[0];
}

__global__ void head_kernel(const float* __restrict__ ymax, const float* __restrict__ We,
                            const float* __restrict__ Wh, const float* __restrict__ bh,
                            float* __restrict__ out)
{
    __shared__ float emb[128];
    __shared__ float yv[512];
    int b = blockIdx.x, t = threadIdx.x;
    for (int s = t; s < 512; s += 128) yv[s] = ymax[(long)b * 512 + s];
    __syncthreads();
    float acc = 0.f;
    for (int c = 0; c < 512; c++) acc = fmaf(yv[c], We[(long)t * 512 + c], acc);
    emb[t] = acc;
    __syncthreads();
    float acc2 = bh[t];
    for (int ff = 0; ff < 128; ff++) acc2 = fmaf(emb[ff], Wh[(long)t * 128 + ff], acc2);
    out[(long)b * 128 + t] = acc2;
}

// ---------------------------------------------------------------------------
extern "C" void kernel_launch(void* const* d_in, const int* in_sizes, int n_in,
                              void* d_out, int out_size, void* d_ws, size_t ws_size,
                              hipStream_t stream)
{
    const float* x = (const float*)d_in[0];
    const float *W[5], *g[5], *bb[5], *m[5], *v[5];
    for (int li = 0; li < 5; li++) {
        W[li]  = (const float*)d_in[1 + li * 5 + 0];
        g[li]  = (const float*)d_in[1 + li * 5 + 1];
        bb[li] = (const float*)d_in[1 + li * 5 + 2];
        m[li]  = (const float*)d_in[1 + li * 5 + 3];
        v[li]  = (const float*)d_in[1 + li * 5 + 4];
    }
    const float* We = (const float*)d_in[26];
    const float* Wh = (const float*)d_in[27];
    const float* bh = (const float*)d_in[28];
    float* out = (float*)d_out;

    // workspace carve (float units). cat is now POINT-MAJOR [b][pt][512].
    float* ws   = (float*)d_ws;
    float* cat  = ws;                                   // 8,388,608; stage4 Y reuses
    float* qbuf = cat + (long)8388608;                  // 8,388,608 multi-purpose
    float* pbuf = qbuf + (long)8388608;                 // 4,194,304 (p-values)
    int*   idxb = (int*)(pbuf + 4194304);               // 327,680 ints
    float* xx   = (float*)(idxb + 327680);              // 16,384
    unsigned short* Wqh = (unsigned short*)(xx + 16384);// 32,768 shorts each
    unsigned short* Wql = Wqh + 32768;
    unsigned short* Wph = Wql + 32768;
    unsigned short* Wpl = Wph + 32768;
    unsigned short* W4h = Wpl + 32768;                  // 262,144 shorts
    unsigned short* W4l = W4h + 262144;
    float* shf  = (float*)(W4l + 262144);               // 512
    float* ymax = shf + 512;                            // 2,048
    unsigned short* Ghi = (unsigned short*)qbuf;        // 2,097,152 shorts max
    unsigned short* Glo = Ghi + 2097152;
    float* knnd = qbuf + 2097152;                       // 1,310,720 floats
    int*   knni = (int*)(qbuf + 2097152 + 1310720);     // 1,310,720 ints
    float* qv   = qbuf + 2097152;                       // 4,194,304 floats (after knn)
    unsigned short* CTh = (unsigned short*)qbuf;        // 8,388,608 shorts
    unsigned short* CTl = CTh + 8388608;

    // ---- stage 0: knn on coords, straight from x (point-major, ldF=3) ----
    sqnorm_pm<<<dim3(16, NB), dim3(256), 0, stream>>>(x, xx, 3, 3, (long)3 * N_PTS);
    to_bf16_pm<<<dim3(64, NB), dim3(256), 0, stream>>>(
        x, (long)3 * N_PTS, 3, 3, 32, Ghi, Glo);
    fused_knn_mfma7<32><<<dim3(64, NSL, NB), dim3(256), 0, stream>>>(
        Ghi, Glo, xx, knnd, knni);
    knn_merge4<<<dim3(64), dim3(256), 0, stream>>>(knnd, knni, idxb);
    edge0_pm<<<dim3(N_PTS / 4, NB), dim3(64, 4), 0, stream>>>(
        x, idxb, W[0], g[0], bb[0], m[0], v[0], cat);

    // ---- stages 1..3 ----
    const int Cs_[3]   = {64, 64, 128};
    const int co_[3]   = {64, 128, 256};
    const int inO_[3]  = {0, 64, 128};
    const int outO_[3] = {64, 128, 256};
    for (int s = 0; s < 3; s++) {
        int C = Cs_[s], cout = co_[s];
        const float* F = cat + inO_[s];                 // row offset within [pt][512]
        sqnorm_pm<<<dim3(16, NB), dim3(256), 0, stream>>>(
            F, xx, C, 512, (long)N_PTS * 512);
        to_bf16_pm<<<dim3(64, NB), dim3(256), 0, stream>>>(
            F, (long)N_PTS * 512, 512, C, C, Ghi, Glo);
        if (C == 64)
            fused_knn_mfma7<64><<<dim3(64, NSL, NB), dim3(256), 0, stream>>>(
                Ghi, Glo, xx, knnd, knni);
        else
            fused_knn_mfma7<128><<<dim3(64, NSL, NB), dim3(256), 0, stream>>>(
                Ghi, Glo, xx, knnd, knni);
        knn_merge4<<<dim3(64), dim3(256), 0, stream>>>(knnd, knni, idxb);

        int li = s + 1;
        fold_edge_bf16<<<dim3((C * cout + 255) / 256), dim3(256), 0, stream>>>(
            W[li], g[li], bb[li], m[li], v[li], Wqh, Wql, Wph, Wpl, shf, C, cout);
        if (C == 64)
            qp_mfma<64><<<dim3(64, cout / 64, NB), dim3(256), 0, stream>>>(
                Ghi, Glo, Wqh, Wql, Wph, Wpl, shf, qv, pbuf, cout);
        else
            qp_mfma<128><<<dim3(64, cout / 64, NB), dim3(256), 0, stream>>>(
                Ghi, Glo, Wqh, Wql, Wph, Wpl, shf, qv, pbuf, cout);
        gather_max_pm<<<dim3(N_PTS / 4, NB), dim3(64, 4), 0, stream>>>(
            qv, pbuf, idxb, cat, cout, outO_[s]);
    }

    // ---- stage 4: MFMA pointwise conv + bn + lrelu ----
    fold_plain_bf16<<<dim3((512 * 512 + 255) / 256), dim3(256), 0, stream>>>(
        W[4], g[4], bb[4], m[4], v[4], W4h, W4l, shf, 512, 512);
    to_bf16_pm<<<dim3(64, NB), dim3(256), 0, stream>>>(
        cat, (long)N_PTS * 512, 512, 512, 512, CTh, CTl);
    conv4_mfma<<<dim3(N_PTS / 16, NB), dim3(256), 0, stream>>>(
        CTh, CTl, W4h, W4l, shf, cat);   // Y (channel-major) overwrites dead cat

    // ---- global max + head ----
    rowmax_kernel<<<dim3(512, NB), dim3(256), 0, stream>>>(cat, ymax);
    head_kernel<<<dim3(NB), dim3(128), 0, stream>>>(ymax, We, Wh, bh, out);
}

// Round 19
// 1061.989 us; speedup vs baseline: 1.3006x; 1.0326x over previous
//
#include <hip/hip_runtime.h>
#include <cfloat>

#define N_PTS 4096
#define NB    4
#define KNN   20
#define EPSB  1e-5f
#define NSL   4          // knn candidate slices per batch-row

typedef short s8v __attribute__((ext_vector_type(8)));
typedef float f4v __attribute__((ext_vector_type(4)));

// ---------------------------------------------------------------------------
// bf16 hi/lo split (round-to-nearest-even both halves)
// ---------------------------------------------------------------------------
__device__ __forceinline__ void bf16split(float x, unsigned short* h, unsigned short* l)
{
    unsigned u = __builtin_bit_cast(unsigned, x);
    unsigned hb = (u + 0x7fffu + ((u >> 16) & 1u)) >> 16;
    float hf = __builtin_bit_cast(float, hb << 16);
    float res = x - hf;
    unsigned u2 = __builtin_bit_cast(unsigned, res);
    unsigned lb = (u2 + 0x7fffu + ((u2 >> 16) & 1u)) >> 16;
    *h = (unsigned short)hb;
    *l = (unsigned short)lb;
}

// ---------------------------------------------------------------------------
// Packed key: fp32 distance (top 24 bits) | 8-bit lane-local ordinal.
// 15 mantissa bits: R10's 11-bit variant FAILED (0.44); this passed (0.03).
// ---------------------------------------------------------------------------
__device__ __forceinline__ unsigned packkey(float d, int lc)
{
    d = fmaxf(d, 0.f);
    unsigned u = __builtin_bit_cast(unsigned, d);
    return (u & 0xFFFFFF00u) | (unsigned)lc;
}

// Branch-free sorted-insert: ascending bubble, 20x (v_min_u32 + v_max_u32).
__device__ __forceinline__ void insert20k(unsigned key, unsigned (&k20)[KNN])
{
#pragma unroll
    for (int j = 0; j < KNN; j++) {
        unsigned old = k20[j];
        unsigned lo = old < key ? old : key;
        key = old < key ? key : old;
        k20[j] = lo;
    }
}

// async global->LDS, 16B per lane; LDS dest = wave-uniform base + lane*16
__device__ __forceinline__ void gl2lds16(const void* g, void* l)
{
    __builtin_amdgcn_global_load_lds(
        (const __attribute__((address_space(1))) unsigned int*)g,
        (__attribute__((address_space(3))) unsigned int*)l,
        16, 0, 0);
}

// 16B-chunk swizzle (involution): chunk g lives at LDS chunk g ^ f(g).
__device__ __forceinline__ int swz(int g)
{
    return g ^ (((g >> 3) ^ (g >> 6)) & 7);
}

// ---------------------------------------------------------------------------
// Point-major fp32 -> bf16 hi/lo (stage-0 only now: x, C=3 -> KDP=32).
// ---------------------------------------------------------------------------
__global__ __launch_bounds__(256)
void to_bf16_pm(const float* __restrict__ F, long bsF, int ldF, int C, int KDP,
                unsigned short* __restrict__ Ghi, unsigned short* __restrict__ Glo)
{
    int b = blockIdx.y;
    int n = blockIdx.x * 64 + (threadIdx.x & 63);
    int kq = threadIdx.x >> 6;
    const float* Fr = F + (long)b * bsF + (long)n * ldF;
    for (int k0 = kq * 8; k0 < KDP; k0 += 32) {
        s8v hv, lv;
#pragma unroll
        for (int i = 0; i < 8; i++) {
            int k = k0 + i;
            float x = (k < C) ? Fr[k] : 0.f;
            unsigned short h, l;
            bf16split(x, &h, &l);
            hv[i] = (short)h;
            lv[i] = (short)l;
        }
        long o = ((long)b * N_PTS + n) * KDP + k0;
        *(s8v*)&Ghi[o] = hv;
        *(s8v*)&Glo[o] = lv;
    }
}

__global__ void sqnorm_pm(const float* __restrict__ F, float* __restrict__ xx,
                          int C, int ldF, long bsF)
{
    int b = blockIdx.y;
    int i = blockIdx.x * 256 + threadIdx.x;
    const float* r = F + (long)b * bsF + (long)i * ldF;
    float s = 0.f;
    for (int c = 0; c < C; c++) s = fmaf(r[c], r[c], s);
    xx[(long)b * N_PTS + i] = s;
}

// ---------------------------------------------------------------------------
// MFMA fused distance + top-20, LDS-staged + XOR swizzle (R17, unchanged).
// ---------------------------------------------------------------------------
template<int KDP>
__global__ __launch_bounds__(256, 3)
void fused_knn_mfma7(const unsigned short* __restrict__ Ghi,
                     const unsigned short* __restrict__ Glo,
                     const float* __restrict__ xx,
                     float* __restrict__ knnd, int* __restrict__ knni)
{
    constexpr int KS = KDP / 32;
    constexpr int TS = 16 * KDP;
    constexpr int NCH = (TS * 2) / 16;
    __shared__ short cbuf[2][2][TS];
    __shared__ unsigned mk[4][16][4][KNN];

    int tid = threadIdx.x;
    int w = tid >> 6, L = tid & 63;
    int n = L & 15;
    int quad = L >> 4;
    int b = blockIdx.z, slice = blockIdx.y;
    int q0 = blockIdx.x * 64, qw = w * 16;
    const unsigned short* Gh = Ghi + (long)b * N_PTS * KDP;
    const unsigned short* Gl = Glo + (long)b * N_PTS * KDP;
    const float* xxb = xx + (long)b * N_PTS;

    s8v qhi[KS], qlo[KS];
    long qbase = (long)(q0 + qw + n) * KDP + quad * 8;
#pragma unroll
    for (int ks = 0; ks < KS; ks++) {
        qhi[ks] = *(const s8v*)&Gh[qbase + ks * 32];
        qlo[ks] = *(const s8v*)&Gl[qbase + ks * 32];
    }
    float xq = xxb[q0 + qw + n];

    unsigned k20[KNN];
#pragma unroll
    for (int j = 0; j < KNN; j++) k20[j] = 0xFFFFFFFFu;

    int po[KS];
#pragma unroll
    for (int ks = 0; ks < KS; ks++) {
        int gL = n * (KDP / 8) + quad + ks * 4;
        po[ks] = swz(gL) * 8;
    }
    int gsrc = swz(tid);

    int w64 = tid & 192;
    {
        long tb = (long)(slice * 1024) * KDP;
        if (tid < NCH) {
            gl2lds16((const char*)(Gh + tb) + gsrc * 16,
                     (char*)&cbuf[0][0][0] + w64 * 16);
            gl2lds16((const char*)(Gl + tb) + gsrc * 16,
                     (char*)&cbuf[0][1][0] + w64 * 16);
        }
    }
    __syncthreads();

    const float* xcp = xxb + slice * 1024 + quad * 4;

    for (int t = 0; t < 64; t++) {
        int cur = t & 1;
        if (t < 63 && tid < NCH) {
            long tb = (long)(slice * 1024 + (t + 1) * 16) * KDP;
            gl2lds16((const char*)(Gh + tb) + gsrc * 16,
                     (char*)&cbuf[cur ^ 1][0][0] + w64 * 16);
            gl2lds16((const char*)(Gl + tb) + gsrc * 16,
                     (char*)&cbuf[cur ^ 1][1][0] + w64 * 16);
        }

        const short* Ch = &cbuf[cur][0][0];
        const short* Cl = &cbuf[cur][1][0];
        f4v acc = {0.f, 0.f, 0.f, 0.f};
#pragma unroll
        for (int ks = 0; ks < KS; ks++) {
            s8v chi = *(const s8v*)&Ch[po[ks]];
            s8v clo = *(const s8v*)&Cl[po[ks]];
            acc = __builtin_amdgcn_mfma_f32_16x16x32_bf16(chi, qhi[ks], acc, 0, 0, 0);
            acc = __builtin_amdgcn_mfma_f32_16x16x32_bf16(chi, qlo[ks], acc, 0, 0, 0);
            acc = __builtin_amdgcn_mfma_f32_16x16x32_bf16(clo, qhi[ks], acc, 0, 0, 0);
        }
        float4 xc4 = *(const float4*)xcp;
        float xcv[4] = {xc4.x, xc4.y, xc4.z, xc4.w};
#pragma unroll
        for (int r = 0; r < 4; r++) {
            float d = xq + xcv[r] - 2.f * acc[r];
            insert20k(packkey(d, t * 4 + r), k20);
        }
        xcp += 16;
        __syncthreads();
    }

#pragma unroll
    for (int j = 0; j < KNN; j++) mk[w][n][quad][j] = k20[j];
    __syncthreads();
    if (L < 16) {
        int p[4] = {0, 0, 0, 0};
        long o = (((long)b * NSL + slice) * N_PTS + (q0 + qw + L)) * KNN;
#pragma unroll
        for (int j = 0; j < KNN; j++) {
            unsigned bd = 0xFFFFFF00u; int bi = 0x7fffffff; int bq = 0;
#pragma unroll
            for (int qd = 0; qd < 4; qd++) {
                unsigned kk = mk[w][L][qd][p[qd]];
                unsigned db = kk & 0xFFFFFF00u;
                int lc = (int)(kk & 0xFFu);
                int ci = slice * 1024 + (lc >> 2) * 16 + qd * 4 + (lc & 3);
                if (db < bd || (db == bd && ci < bi)) { bd = db; bi = ci; bq = qd; }
            }
            knnd[o + j] = __builtin_bit_cast(float, bd);
            knni[o + j] = bi;
            p[bq]++;
        }
    }
}

// ---------------------------------------------------------------------------
__global__ void knn_merge4(const float* __restrict__ knnd, const int* __restrict__ knni,
                           int* __restrict__ idxOut)
{
    int id = blockIdx.x * 256 + threadIdx.x;
    int b = id / N_PTS, i = id % N_PTS;
    const float* dl[NSL]; const int* il[NSL];
#pragma unroll
    for (int qt = 0; qt < NSL; qt++) {
        dl[qt] = knnd + (((long)b * NSL + qt) * N_PTS + i) * KNN;
        il[qt] = knni + (((long)b * NSL + qt) * N_PTS + i) * KNN;
    }
    int p[NSL];
#pragma unroll
    for (int qt = 0; qt < NSL; qt++) p[qt] = 0;
    int* o = idxOut + (long)id * KNN;
#pragma unroll
    for (int j = 0; j < KNN; j++) {
        float best = FLT_MAX; int bi = 0x7fffffff; int bq = 0;
#pragma unroll
        for (int qt = 0; qt < NSL; qt++) {
            float vv = (p[qt] < KNN) ? dl[qt][p[qt]] : FLT_MAX;
            int   ci = (p[qt] < KNN) ? il[qt][p[qt]] : 0x7fffffff;
            if (vv < best || (vv == best && ci < bi)) { best = vv; bi = ci; bq = qt; }
        }
        o[j] = bi;
        p[bq]++;
    }
}

// ---------------------------------------------------------------------------
// Fused q/p MFMA GEMM (edge stages) — unchanged.
// ---------------------------------------------------------------------------
template<int KDP>
__global__ __launch_bounds__(256)
void qp_mfma(const unsigned short* __restrict__ Ghi,
             const unsigned short* __restrict__ Glo,
             const unsigned short* __restrict__ Wqh, const unsigned short* __restrict__ Wql,
             const unsigned short* __restrict__ Wph, const unsigned short* __restrict__ Wpl,
             const float* __restrict__ shf,
             float* __restrict__ qv, float* __restrict__ pv, int cout)
{
    constexpr int KS = KDP / 32;
    int tid = threadIdx.x;
    int w = tid >> 6, L = tid & 63;
    int n = L & 15, quad = L >> 4;
    int b = blockIdx.z;
    int p0 = blockIdx.x * 64 + w * 16;

    s8v ah[KS], al[KS];
    long abase = ((long)b * N_PTS + p0 + n) * KDP + quad * 8;
#pragma unroll
    for (int ks = 0; ks < KS; ks++) {
        ah[ks] = *(const s8v*)&Ghi[abase + ks * 32];
        al[ks] = *(const s8v*)&Glo[abase + ks * 32];
    }

#pragma unroll
    for (int oc4 = 0; oc4 < 4; oc4++) {
        int oc = blockIdx.y * 4 + oc4;
        long wbase = (long)(oc * 16 + n) * KDP + quad * 8;
        f4v aq = {0.f, 0.f, 0.f, 0.f};
        f4v ap = {0.f, 0.f, 0.f, 0.f};
#pragma unroll
        for (int ks = 0; ks < KS; ks++) {
            s8v wh = *(const s8v*)&Wqh[wbase + ks * 32];
            s8v wl = *(const s8v*)&Wql[wbase + ks * 32];
            aq = __builtin_amdgcn_mfma_f32_16x16x32_bf16(ah[ks], wh, aq, 0, 0, 0);
            aq = __builtin_amdgcn_mfma_f32_16x16x32_bf16(ah[ks], wl, aq, 0, 0, 0);
            aq = __builtin_amdgcn_mfma_f32_16x16x32_bf16(al[ks], wh, aq, 0, 0, 0);
            s8v ph = *(const s8v*)&Wph[wbase + ks * 32];
            s8v pl = *(const s8v*)&Wpl[wbase + ks * 32];
            ap = __builtin_amdgcn_mfma_f32_16x16x32_bf16(ah[ks], ph, ap, 0, 0, 0);
            ap = __builtin_amdgcn_mfma_f32_16x16x32_bf16(ah[ks], pl, ap, 0, 0, 0);
            ap = __builtin_amdgcn_mfma_f32_16x16x32_bf16(al[ks], ph, ap, 0, 0, 0);
        }
        float sv = shf[oc * 16 + n];
#pragma unroll
        for (int r = 0; r < 4; r++) {
            long pt = p0 + quad * 4 + r;
            long o = ((long)b * N_PTS + pt) * cout + oc * 16 + n;
            qv[o] = aq[r];
            pv[o] = ap[r] + sv;
        }
    }
}

// ---------------------------------------------------------------------------
// Stage-4 MFMA conv reading fp32 cat directly (on-the-fly hi/lo split).
// Y (channel-major) written to a SEPARATE buffer (cat stays readable).
// grid (N/16, B), block 256.
// ---------------------------------------------------------------------------
__global__ __launch_bounds__(256)
void conv4f_mfma(const float* __restrict__ cat,
                 const unsigned short* __restrict__ W4h, const unsigned short* __restrict__ W4l,
                 const float* __restrict__ shf, float* __restrict__ Y)
{
    int tid = threadIdx.x;
    int w = tid >> 6, L = tid & 63;
    int n = L & 15, quad = L >> 4;
    int b = blockIdx.y;
    int p0 = blockIdx.x * 16;
    const float* cr = cat + ((long)b * N_PTS + p0 + n) * 512 + quad * 8;

    f4v acc[8];
#pragma unroll
    for (int ch = 0; ch < 8; ch++) acc[ch] = {0.f, 0.f, 0.f, 0.f};

    for (int ks = 0; ks < 16; ks++) {
        float4 f0 = *(const float4*)&cr[ks * 32];
        float4 f1 = *(const float4*)&cr[ks * 32 + 4];
        float fv[8] = {f0.x, f0.y, f0.z, f0.w, f1.x, f1.y, f1.z, f1.w};
        s8v bh, bl;
#pragma unroll
        for (int i = 0; i < 8; i++) {
            unsigned short h, l;
            bf16split(fv[i], &h, &l);
            bh[i] = (short)h;
            bl[i] = (short)l;
        }
#pragma unroll
        for (int ch = 0; ch < 8; ch++) {
            long o = (long)((w * 8 + ch) * 16 + n) * 512 + quad * 8 + ks * 32;
            s8v ahv = *(const s8v*)&W4h[o];
            s8v alv = *(const s8v*)&W4l[o];
            acc[ch] = __builtin_amdgcn_mfma_f32_16x16x32_bf16(ahv, bh, acc[ch], 0, 0, 0);
            acc[ch] = __builtin_amdgcn_mfma_f32_16x16x32_bf16(ahv, bl, acc[ch], 0, 0, 0);
            acc[ch] = __builtin_amdgcn_mfma_f32_16x16x32_bf16(alv, bh, acc[ch], 0, 0, 0);
        }
    }
#pragma unroll
    for (int ch = 0; ch < 8; ch++) {
#pragma unroll
        for (int r = 0; r < 4; r++) {
            int o = (w * 8 + ch) * 16 + quad * 4 + r;
            float y = acc[ch][r] + shf[o];
            y = y >= 0.f ? y : 0.2f * y;
            Y[((long)b * 512 + o) * N_PTS + p0 + n] = y;
        }
    }
}

// ---------------------------------------------------------------------------
// Weight folding to bf16 hi/lo, [o][c] layout.
// ---------------------------------------------------------------------------
__global__ void fold_edge_bf16(const float* __restrict__ W, const float* __restrict__ g,
                               const float* __restrict__ bb, const float* __restrict__ m,
                               const float* __restrict__ v,
                               unsigned short* __restrict__ Wqh, unsigned short* __restrict__ Wql,
                               unsigned short* __restrict__ Wph, unsigned short* __restrict__ Wpl,
                               float* __restrict__ shift, int C, int cout)
{
    int id = blockIdx.x * 256 + threadIdx.x;
    if (id < C * cout) {
        int o = id / C;
        int c = id % C;
        float sc = g[o] * rsqrtf(v[o] + EPSB);
        float wd = W[(long)o * 2 * C + c];
        float wc = W[(long)o * 2 * C + C + c];
        bf16split(sc * wd, &Wqh[id], &Wql[id]);
        bf16split(sc * (wc - wd), &Wph[id], &Wpl[id]);
    }
    if (id < cout) {
        float sc = g[id] * rsqrtf(v[id] + EPSB);
        shift[id] = bb[id] - m[id] * sc;
    }
}

__global__ void fold_plain_bf16(const float* __restrict__ W, const float* __restrict__ g,
                                const float* __restrict__ bb, const float* __restrict__ m,
                                const float* __restrict__ v,
                                unsigned short* __restrict__ W4h, unsigned short* __restrict__ W4l,
                                float* __restrict__ shift, int C, int cout)
{
    int id = blockIdx.x * 256 + threadIdx.x;
    if (id < C * cout) {
        int o = id / C;
        int c = id % C;
        float sc = g[o] * rsqrtf(v[o] + EPSB);
        bf16split(sc * W[(long)o * C + c], &W4h[id], &W4l[id]);
    }
    if (id < cout) {
        float sc = g[id] * rsqrtf(v[id] + EPSB);
        shift[id] = bb[id] - m[id] * sc;
    }
}

// ---------------------------------------------------------------------------
// Gather+max writing cat slice AND (optionally) next stage's bf16 hi/lo G
// arrays + squared norms xx in one pass. grid (N/4, B), block (64,4).
// Ghi==nullptr (wave-uniform) disables emission (last edge stage).
// ---------------------------------------------------------------------------
__global__ void gather_max_fused(const float* __restrict__ q, const float* __restrict__ p,
                                 const int* __restrict__ idx, float* __restrict__ cat,
                                 int cout, int c_off,
                                 unsigned short* __restrict__ Ghi,
                                 unsigned short* __restrict__ Glo,
                                 float* __restrict__ xx)
{
    int b = blockIdx.y;
    int i = blockIdx.x * 4 + threadIdx.y;
    int tx = threadIdx.x;
    const int* ip = idx + ((long)b * N_PTS + i) * KNN;
    int js[KNN];
#pragma unroll
    for (int k = 0; k < KNN; k++) js[k] = ip[k];
    const float* qb = q + (long)b * N_PTS * cout;
    const float* pb = p + ((long)b * N_PTS + i) * cout;
    float* ob = cat + ((long)b * N_PTS + i) * 512 + c_off;
    float ssum = 0.f;
    for (int o0 = 0; o0 < cout; o0 += 64) {
        int o = o0 + tx;
        float pv = pb[o];
        float mx = -FLT_MAX;
#pragma unroll
        for (int k = 0; k < KNN; k++) {
            float val = qb[(long)js[k] * cout + o] + pv;
            val = val >= 0.f ? val : 0.2f * val;
            mx = fmaxf(mx, val);
        }
        ob[o] = mx;
        if (Ghi) {
            unsigned short h, l;
            bf16split(mx, &h, &l);
            long go = ((long)b * N_PTS + i) * cout + o;
            Ghi[go] = h;
            Glo[go] = l;
            ssum = fmaf(mx, mx, ssum);
        }
    }
    if (Ghi) {
#pragma unroll
        for (int off = 32; off > 0; off >>= 1) ssum += __shfl_xor(ssum, off);
        if (tx == 0) xx[(long)b * N_PTS + i] = ssum;
    }
}

// ---------------------------------------------------------------------------
// Block-0 edge conv, fused: cat slice + G arrays (KDP=64) + xx in one pass.
// grid (N/4, B), block (64,4): wave = one point, lanes = 64 channels.
// ---------------------------------------------------------------------------
__global__ void edge0_fused(const float* __restrict__ x, const int* __restrict__ idx,
                            const float* __restrict__ W0, const float* __restrict__ g0,
                            const float* __restrict__ b0, const float* __restrict__ m0,
                            const float* __restrict__ v0, float* __restrict__ cat,
                            unsigned short* __restrict__ Ghi,
                            unsigned short* __restrict__ Glo,
                            float* __restrict__ xx)
{
    int b = blockIdx.y;
    int i = blockIdx.x * 4 + threadIdx.y;
    int o = threadIdx.x;
    const float* xc = x + ((long)b * N_PTS + i) * 3;
    float cx = xc[0], cy = xc[1], cz = xc[2];
    float w[9];
#pragma unroll
    for (int c = 0; c < 9; c++) w[c] = W0[o * 9 + c];
    float sc = g0[o] * rsqrtf(v0[o] + EPSB);
    float sh = b0[o] - m0[o] * sc;
    const int* ip = idx + ((long)b * N_PTS + i) * KNN;
    float mx = -FLT_MAX;
#pragma unroll
    for (int k = 0; k < KNN; k++) {
        const float* xn = x + ((long)b * N_PTS + ip[k]) * 3;
        float nx = xn[0], ny = xn[1], nz = xn[2];
        float dx = nx - cx, dy = ny - cy, dz = nz - cz;
        float crx = cy * nz - cz * ny;
        float cry = cz * nx - cx * nz;
        float crz = cx * ny - cy * nx;
        float y = w[0] * dx + w[1] * dy + w[2] * dz
                + w[3] * crx + w[4] * cry + w[5] * crz
                + w[6] * cx + w[7] * cy + w[8] * cz;
        y = y * sc + sh;
        y = y >= 0.f ? y : 0.2f * y;
        mx = fmaxf(mx, y);
    }
    cat[((long)b * N_PTS + i) * 512 + o] = mx;
    unsigned short h, l;
    bf16split(mx, &h, &l);
    long go = ((long)b * N_PTS + i) * 64 + o;
    Ghi[go] = h;
    Glo[go] = l;
    float ssum = mx * mx;
#pragma unroll
    for (int off = 32; off > 0; off >>= 1) ssum += __shfl_xor(ssum, off);
    if (o == 0) xx[(long)b * N_PTS + i] = ssum;
}

__global__ void rowmax_kernel(const float* __restrict__ Y, float* __restrict__ ymax)
{
    __shared__ float red[256];
    int b = blockIdx.y, o = blockIdx.x, t = threadIdx.x;
    const float* yb = Y + ((long)b * 512 + o) * N_PTS;
    float mx = -FLT_MAX;
#pragma unroll
    for (int s = 0; s < N_PTS / 256; s++) mx = fmaxf(mx, yb[t + 256 * s]);
    red[t] = mx;
    __syncthreads();
    for (int off = 128; off > 0; off >>= 1) {
        if (t < off) red[t] = fmaxf(red[t], red[t + off]);
        __syncthreads();
    }
    if (t == 0) ymax[(long)b * 512 + o] = red[0];
}

__global__ void head_kernel(const float* __restrict__ ymax, const float* __restrict__ We,
                            const float* __restrict__ Wh, const float* __restrict__ bh,
                            float* __restrict__ out)
{
    __shared__ float emb[128];
    __shared__ float yv[512];
    int b = blockIdx.x, t = threadIdx.x;
    for (int s = t; s < 512; s += 128) yv[s] = ymax[(long)b * 512 + s];
    __syncthreads();
    float acc = 0.f;
    for (int c = 0; c < 512; c++) acc = fmaf(yv[c], We[(long)t * 512 + c], acc);
    emb[t] = acc;
    __syncthreads();
    float acc2 = bh[t];
    for (int ff = 0; ff < 128; ff++) acc2 = fmaf(emb[ff], Wh[(long)t * 128 + ff], acc2);
    out[(long)b * 128 + t] = acc2;
}

// ---------------------------------------------------------------------------
extern "C" void kernel_launch(void* const* d_in, const int* in_sizes, int n_in,
                              void* d_out, int out_size, void* d_ws, size_t ws_size,
                              hipStream_t stream)
{
    const float* x = (const float*)d_in[0];
    const float *W[5], *g[5], *bb[5], *m[5], *v[5];
    for (int li = 0; li < 5; li++) {
        W[li]  = (const float*)d_in[1 + li * 5 + 0];
        g[li]  = (const float*)d_in[1 + li * 5 + 1];
        bb[li] = (const float*)d_in[1 + li * 5 + 2];
        m[li]  = (const float*)d_in[1 + li * 5 + 3];
        v[li]  = (const float*)d_in[1 + li * 5 + 4];
    }
    const float* We = (const float*)d_in[26];
    const float* Wh = (const float*)d_in[27];
    const float* bh = (const float*)d_in[28];
    float* out = (float*)d_out;

    // workspace carve (float units). cat POINT-MAJOR [b][pt][512].
    float* ws   = (float*)d_ws;
    float* cat  = ws;                                   // 8,388,608
    float* qbuf = cat + (long)8388608;                  // 8,388,608 multi-purpose; stage-4 Y
    float* pbuf = qbuf + (long)8388608;                 // 4,194,304 (p-values)
    int*   idxb = (int*)(pbuf + 4194304);               // 327,680 ints
    float* xx   = (float*)(idxb + 327680);              // 16,384
    unsigned short* Wqh = (unsigned short*)(xx + 16384);// 32,768 shorts each
    unsigned short* Wql = Wqh + 32768;
    unsigned short* Wph = Wql + 32768;
    unsigned short* Wpl = Wph + 32768;
    unsigned short* W4h = Wpl + 32768;                  // 262,144 shorts
    unsigned short* W4l = W4h + 262144;
    float* shf  = (float*)(W4l + 262144);               // 512
    float* ymax = shf + 512;                            // 2,048
    unsigned short* Ghi = (unsigned short*)qbuf;        // 2,097,152 shorts max
    unsigned short* Glo = Ghi + 2097152;
    float* knnd = qbuf + 2097152;                       // 1,310,720 floats
    int*   knni = (int*)(qbuf + 2097152 + 1310720);     // 1,310,720 ints
    float* qv   = qbuf + 2097152;                       // 4,194,304 floats (after knn)
    float* Ybuf = qbuf;                                 // stage-4 Y (8,388,608; all qbuf dead)

    // ---- stage 0: knn on coords, straight from x ----
    sqnorm_pm<<<dim3(16, NB), dim3(256), 0, stream>>>(x, xx, 3, 3, (long)3 * N_PTS);
    to_bf16_pm<<<dim3(64, NB), dim3(256), 0, stream>>>(
        x, (long)3 * N_PTS, 3, 3, 32, Ghi, Glo);
    fused_knn_mfma7<32><<<dim3(64, NSL, NB), dim3(256), 0, stream>>>(
        Ghi, Glo, xx, knnd, knni);
    knn_merge4<<<dim3(64), dim3(256), 0, stream>>>(knnd, knni, idxb);
    // edge0 emits cat[0:64] + G arrays (KDP=64) + xx for stage-1 knn
    edge0_fused<<<dim3(N_PTS / 4, NB), dim3(64, 4), 0, stream>>>(
        x, idxb, W[0], g[0], bb[0], m[0], v[0], cat, Ghi, Glo, xx);

    // ---- stages 1..3 ----
    const int Cs_[3]   = {64, 64, 128};
    const int co_[3]   = {64, 128, 256};
    const int outO_[3] = {64, 128, 256};
    for (int s = 0; s < 3; s++) {
        int C = Cs_[s], cout = co_[s];
        // G/xx for this stage were emitted by the previous producer
        if (C == 64)
            fused_knn_mfma7<64><<<dim3(64, NSL, NB), dim3(256), 0, stream>>>(
                Ghi, Glo, xx, knnd, knni);
        else
            fused_knn_mfma7<128><<<dim3(64, NSL, NB), dim3(256), 0, stream>>>(
                Ghi, Glo, xx, knnd, knni);
        knn_merge4<<<dim3(64), dim3(256), 0, stream>>>(knnd, knni, idxb);

        int li = s + 1;
        fold_edge_bf16<<<dim3((C * cout + 255) / 256), dim3(256), 0, stream>>>(
            W[li], g[li], bb[li], m[li], v[li], Wqh, Wql, Wph, Wpl, shf, C, cout);
        if (C == 64)
            qp_mfma<64><<<dim3(64, cout / 64, NB), dim3(256), 0, stream>>>(
                Ghi, Glo, Wqh, Wql, Wph, Wpl, shf, qv, pbuf, cout);
        else
            qp_mfma<128><<<dim3(64, cout / 64, NB), dim3(256), 0, stream>>>(
                Ghi, Glo, Wqh, Wql, Wph, Wpl, shf, qv, pbuf, cout);
        // emit next stage's G/xx for s=0,1 (next C == cout); s=2 has no next knn
        if (s < 2)
            gather_max_fused<<<dim3(N_PTS / 4, NB), dim3(64, 4), 0, stream>>>(
                qv, pbuf, idxb, cat, cout, outO_[s], Ghi, Glo, xx);
        else
            gather_max_fused<<<dim3(N_PTS / 4, NB), dim3(64, 4), 0, stream>>>(
                qv, pbuf, idxb, cat, cout, outO_[s],
                (unsigned short*)nullptr, (unsigned short*)nullptr, (float*)nullptr);
    }

    // ---- stage 4: MFMA pointwise conv reading fp32 cat directly ----
    fold_plain_bf16<<<dim3((512 * 512 + 255) / 256), dim3(256), 0, stream>>>(
        W[4], g[4], bb[4], m[4], v[4], W4h, W4l, shf, 512, 512);
    conv4f_mfma<<<dim3(N_PTS / 16, NB), dim3(256), 0, stream>>>(
        cat, W4h, W4l, shf, Ybuf);       // Y -> qbuf (cat must stay readable)

    // ---- global max + head ----
    rowmax_kernel<<<dim3(512, NB), dim3(256), 0, stream>>>(Ybuf, ymax);
    head_kernel<<<dim3(NB), dim3(128), 0, stream>>>(ymax, We, Wh, bh, out);
}